// Round 1
// baseline (4238.673 us; speedup 1.0000x reference)
//
#include <hip/hip_runtime.h>

typedef __fp16 f16;
typedef __fp16 f16x4 __attribute__((ext_vector_type(4)));
typedef __fp16 f16x8 __attribute__((ext_vector_type(8)));
typedef float  f32x4 __attribute__((ext_vector_type(4)));

#define DEV static __device__ __forceinline__

DEV f32x4 mfma16(f16x4 a, f16x4 b, f32x4 c) {
  return __builtin_amdgcn_mfma_f32_16x16x16f16(a, b, c, 0, 0, 0);
}
DEV f16x4 lo4(f16x8 v) { return __builtin_shufflevector(v, v, 0, 1, 2, 3); }
DEV f16x4 hi4(f16x8 v) { return __builtin_shufflevector(v, v, 4, 5, 6, 7); }
DEV float sigf(float x) { return 1.f / (1.f + __expf(-x)); }
DEV float tanh_(float x) { float e = __expf(2.f * x); return 1.f - 2.f / (e + 1.f); }

union U8 { float4 f4; float2 f2[2]; };

// ---------------- prologue kernels ----------------

__global__ void k_convert4(const float* __restrict__ src, f16* __restrict__ dst, int n4) {
  int i = blockIdx.x * 256 + threadIdx.x;
  if (i < n4) {
    float4 v = ((const float4*)src)[i];
    f16x4 o = { (f16)v.x, (f16)v.y, (f16)v.z, (f16)v.w };
    *(f16x4*)(dst + (size_t)i * 4) = o;
  }
}

// att_conv_w [e][f][3][3] -> wc9 [e][r*512+f]  (r = kh*3+kw)
__global__ void k_wc9(const float* __restrict__ src, f16* __restrict__ dst) {
  int i = blockIdx.x * 256 + threadIdx.x;
  if (i < 512 * 4608) {
    int e = i / 4608, k = i % 4608;
    int rr = k / 512, f = k % 512;
    dst[i] = (f16)src[(size_t)e * 4608 + f * 9 + rr];
  }
}

// conv_f [b][f][240] -> cfT [b][240][512] fp16
__global__ void k_cfT(const float* __restrict__ cf, f16* __restrict__ dst) {
  int i = blockIdx.x * 256 + threadIdx.x;
  if (i < 64 * 240 * 512) {
    int b = i / (240 * 512), r = i % (240 * 512);
    int p = r / 512, f = r % 512;
    dst[i] = (f16)cf[((size_t)b * 512 + f) * 240 + p];
  }
}

// x_seq [w][b][f] = max_h conv_f[b][f][h][w]
__global__ void k_maxpool(const float* __restrict__ cf, f16* __restrict__ xseq) {
  int i = blockIdx.x * 256 + threadIdx.x;
  if (i < 40 * 64 * 512) {
    int w = i / (64 * 512), r = i % (64 * 512);
    int b = r / 512, f = r % 512;
    const float* base = cf + ((size_t)b * 512 + f) * 240 + w;
    float m = base[0];
#pragma unroll
    for (int h = 1; h < 6; ++h) m = fmaxf(m, base[h * 40]);
    xseq[i] = (f16)m;
  }
}

__global__ void k_ltarget(const int* __restrict__ target, int* __restrict__ lt) {
  int b = threadIdx.x;
  if (b >= 64) return;
  int row[32];
  row[0] = 0;
  for (int t = 1; t <= 30; ++t) row[t] = target[b * 30 + t - 1];
  row[31] = 0;
  int j = 1;
  while (row[j] != 0) ++j;   // row[31]==0 guarantees termination
  row[j] = 95;               // END
  for (int t = 0; t < 32; ++t) lt[b * 32 + t] = row[t];
}

// xs[0] = holistic (h_en layer1), xs[t>=1] = embed(gt[t-1]); gt = [START, target...]
__global__ void k_fill_xs(const f16* __restrict__ hol, const f16* __restrict__ emb,
                          const int* __restrict__ tgt, f16* __restrict__ xs) {
  int i = blockIdx.x * 256 + threadIdx.x;
  if (i < 32 * 64 * 512) {
    int t = i / (64 * 512), r = i % (64 * 512);
    int b = r / 512, u = r % 512;
    f16 v;
    if (t == 0) v = hol[b * 512 + u];
    else {
      int tok = (t == 1) ? 95 : tgt[b * 30 + t - 2];
      v = emb[(size_t)tok * 512 + u];
    }
    xs[i] = v;
  }
}

// ---------------- LSTM cell: gates MFMA GEMM + fused pointwise ----------------
// grid 32 (utile: 16 u's), block 256 (wave = gate)
__global__ __launch_bounds__(256) void k_lstm_step(
    const f16* __restrict__ x,    // [64][512]
    const f16* __restrict__ hin,  // [64][512]
    const f16* __restrict__ wih,  // [2048][512]
    const f16* __restrict__ whh,  // [2048][512]
    const float* __restrict__ bih,
    const float* __restrict__ bhh,
    float* __restrict__ c,        // [64][512]
    f16* __restrict__ hout)       // [64][512]
{
  __shared__ f16 At[64][72];
  __shared__ f16 Bt[64][72];
  __shared__ float G[4][64][17];
  const int t = threadIdx.x, lane = t & 63, g = t >> 6;
  const int utile = blockIdx.x;
  f32x4 acc[4] = {};
  const int m16 = lane & 15, g4 = lane >> 4;

  for (int ph = 0; ph < 2; ++ph) {
    const f16* src = ph ? hin : x;
    const f16* wsrc = ph ? whh : wih;
    for (int k0 = 0; k0 < 512; k0 += 64) {
      __syncthreads();
      {  // stage A [64][64] with k-permuted cols: col' = (j>>2)*16 + ch*4 + (j&3)
        int row = t >> 2, ch = t & 3;
        const f16* s = src + (size_t)row * 512 + k0 + ch * 16;
        U8 u0, u1;
        u0.f4 = *(const float4*)s;
        u1.f4 = *(const float4*)(s + 8);
        *(float2*)&At[row][ 0 + ch * 4] = u0.f2[0];
        *(float2*)&At[row][16 + ch * 4] = u0.f2[1];
        *(float2*)&At[row][32 + ch * 4] = u1.f2[0];
        *(float2*)&At[row][48 + ch * 4] = u1.f2[1];
      }
      {  // stage B: row n = gate*16 + within  ->  j = gate*512 + utile*16 + within
        int row = t >> 2, ch = t & 3;
        int jg = (row >> 4) * 512 + utile * 16 + (row & 15);
        const f16* s = wsrc + (size_t)jg * 512 + k0 + ch * 16;
        U8 u0, u1;
        u0.f4 = *(const float4*)s;
        u1.f4 = *(const float4*)(s + 8);
        *(float2*)&Bt[row][ 0 + ch * 4] = u0.f2[0];
        *(float2*)&Bt[row][16 + ch * 4] = u0.f2[1];
        *(float2*)&Bt[row][32 + ch * 4] = u1.f2[0];
        *(float2*)&Bt[row][48 + ch * 4] = u1.f2[1];
      }
      __syncthreads();
#pragma unroll
      for (int half = 0; half < 2; ++half) {
        f16x8 bf = *(const f16x8*)&Bt[g * 16 + m16][g4 * 16 + half * 8];
        f16x4 bl = lo4(bf), bh = hi4(bf);
#pragma unroll
        for (int mt = 0; mt < 4; ++mt) {
          f16x8 af = *(const f16x8*)&At[mt * 16 + m16][g4 * 16 + half * 8];
          acc[mt] = mfma16(lo4(af), bl, acc[mt]);
          acc[mt] = mfma16(hi4(af), bh, acc[mt]);
        }
      }
    }
  }
  // bias + gates to LDS
  {
    int jg = g * 512 + utile * 16 + m16;
    float bias = bih[jg] + bhh[jg];
#pragma unroll
    for (int mt = 0; mt < 4; ++mt)
#pragma unroll
      for (int r = 0; r < 4; ++r)
        G[g][mt * 16 + g4 * 4 + r][m16] = acc[mt][r] + bias;
  }
  __syncthreads();
  // pointwise: 1024 (b,u) outputs, 4 per thread
#pragma unroll
  for (int oi = 0; oi < 4; ++oi) {
    int idx = t + oi * 256;
    int b = idx >> 4, uo = idx & 15;
    float gi = G[0][b][uo], gf = G[1][b][uo], gg = G[2][b][uo], go = G[3][b][uo];
    int off = b * 512 + utile * 16 + uo;
    float cold = c[off];
    float cn = sigf(gf) * cold + sigf(gi) * tanh_(gg);
    float hn = sigf(go) * tanh_(cn);
    c[off] = cn;
    hout[off] = (f16)hn;
  }
}

// ---------------- g_em = hlast @ att_wh^T + bh  (MFMA) ----------------
__global__ __launch_bounds__(256) void k_gemm64(
    const f16* __restrict__ x,    // [64][512]
    const f16* __restrict__ wn,   // [512][512] row-major [n][k]
    const float* __restrict__ bias,
    float* __restrict__ outm)     // [64][512]
{
  __shared__ f16 At[64][72];
  __shared__ f16 Bt[64][72];
  const int t = threadIdx.x, lane = t & 63, g = t >> 6;
  f32x4 acc[4] = {};
  const int m16 = lane & 15, g4 = lane >> 4;

  for (int k0 = 0; k0 < 512; k0 += 64) {
    __syncthreads();
    {
      int row = t >> 2, ch = t & 3;
      const f16* s = x + (size_t)row * 512 + k0 + ch * 16;
      U8 u0, u1;
      u0.f4 = *(const float4*)s; u1.f4 = *(const float4*)(s + 8);
      *(float2*)&At[row][ 0 + ch * 4] = u0.f2[0];
      *(float2*)&At[row][16 + ch * 4] = u0.f2[1];
      *(float2*)&At[row][32 + ch * 4] = u1.f2[0];
      *(float2*)&At[row][48 + ch * 4] = u1.f2[1];
    }
    {
      int row = t >> 2, ch = t & 3;
      int jg = blockIdx.x * 64 + row;
      const f16* s = wn + (size_t)jg * 512 + k0 + ch * 16;
      U8 u0, u1;
      u0.f4 = *(const float4*)s; u1.f4 = *(const float4*)(s + 8);
      *(float2*)&Bt[row][ 0 + ch * 4] = u0.f2[0];
      *(float2*)&Bt[row][16 + ch * 4] = u0.f2[1];
      *(float2*)&Bt[row][32 + ch * 4] = u1.f2[0];
      *(float2*)&Bt[row][48 + ch * 4] = u1.f2[1];
    }
    __syncthreads();
#pragma unroll
    for (int half = 0; half < 2; ++half) {
      f16x8 bf = *(const f16x8*)&Bt[g * 16 + m16][g4 * 16 + half * 8];
      f16x4 bl = lo4(bf), bh = hi4(bf);
#pragma unroll
      for (int mt = 0; mt < 4; ++mt) {
        f16x8 af = *(const f16x8*)&At[mt * 16 + m16][g4 * 16 + half * 8];
        acc[mt] = mfma16(lo4(af), bl, acc[mt]);
        acc[mt] = mfma16(hi4(af), bh, acc[mt]);
      }
    }
  }
  int e = blockIdx.x * 64 + g * 16 + m16;
  float bias_e = bias[e];
#pragma unroll
  for (int mt = 0; mt < 4; ++mt)
#pragma unroll
    for (int r = 0; r < 4; ++r) {
      int b = mt * 16 + g4 * 4 + r;
      outm[b * 512 + e] = acc[mt][r] + bias_e;
    }
}

// ---------------- conv 3x3 as 9 shifted MFMA GEMMs ----------------
// grid (4, 64): x = e-tile (128 cols), y = b.  block 256 = 4 waves, wave: 15m x 2n tiles.
__global__ __launch_bounds__(256, 1) void k_conv(
    const f16* __restrict__ cfT,  // [64][240][512]
    const f16* __restrict__ wc9,  // [512][4608] (k = r*512+f)
    const float* __restrict__ cb, // [512]
    float* __restrict__ xem)      // [64][240][512]
{
  __shared__ f16 At[240][40];
  __shared__ f16 Bt[128][40];
  const int t = threadIdx.x, lane = t & 63, w = t >> 6;
  const int b = blockIdx.y, eb = blockIdx.x * 128;
  const int m16 = lane & 15, g4 = lane >> 4;
  f32x4 acc[15][2] = {};

  for (int kr = 0; kr < 9; ++kr) {
    int dh = kr / 3 - 1, dw = kr % 3 - 1;
    for (int f0 = 0; f0 < 512; f0 += 32) {
      __syncthreads();
      if (t < 240) {  // stage A row p=t with halo shift; col' = (j>>2)*8 + ch*4 + (j&3)
        int hh = t / 40 + dh, ww = t % 40 + dw;
        if (hh >= 0 && hh < 6 && ww >= 0 && ww < 40) {
          const f16* s = cfT + ((size_t)(b * 240 + hh * 40 + ww) * 512 + f0);
          U8 u0, u1, u2, u3;
          u0.f4 = *(const float4*)s;        u1.f4 = *(const float4*)(s + 8);
          u2.f4 = *(const float4*)(s + 16); u3.f4 = *(const float4*)(s + 24);
          *(float2*)&At[t][ 0] = u0.f2[0];
          *(float2*)&At[t][ 8] = u0.f2[1];
          *(float2*)&At[t][16] = u1.f2[0];
          *(float2*)&At[t][24] = u1.f2[1];
          *(float2*)&At[t][ 4] = u2.f2[0];
          *(float2*)&At[t][12] = u2.f2[1];
          *(float2*)&At[t][20] = u3.f2[0];
          *(float2*)&At[t][28] = u3.f2[1];
        } else {
          float2 z = make_float2(0.f, 0.f);
          *(float2*)&At[t][ 0] = z; *(float2*)&At[t][ 8] = z;
          *(float2*)&At[t][16] = z; *(float2*)&At[t][24] = z;
          *(float2*)&At[t][ 4] = z; *(float2*)&At[t][12] = z;
          *(float2*)&At[t][20] = z; *(float2*)&At[t][28] = z;
        }
      }
      {  // stage B: 128 rows x 32
        int n = t >> 1, ch = t & 1;
        const f16* s = wc9 + (size_t)(eb + n) * 4608 + kr * 512 + f0 + ch * 16;
        U8 u0, u1;
        u0.f4 = *(const float4*)s; u1.f4 = *(const float4*)(s + 8);
        *(float2*)&Bt[n][ 0 + ch * 4] = u0.f2[0];
        *(float2*)&Bt[n][ 8 + ch * 4] = u0.f2[1];
        *(float2*)&Bt[n][16 + ch * 4] = u1.f2[0];
        *(float2*)&Bt[n][24 + ch * 4] = u1.f2[1];
      }
      __syncthreads();
      f16x8 b0 = *(const f16x8*)&Bt[w * 32 + m16][g4 * 8];
      f16x8 b1 = *(const f16x8*)&Bt[w * 32 + 16 + m16][g4 * 8];
      f16x4 b0l = lo4(b0), b0h = hi4(b0), b1l = lo4(b1), b1h = hi4(b1);
#pragma unroll
      for (int mt = 0; mt < 15; ++mt) {
        f16x8 af = *(const f16x8*)&At[mt * 16 + m16][g4 * 8];
        f16x4 al = lo4(af), ah = hi4(af);
        acc[mt][0] = mfma16(al, b0l, acc[mt][0]);
        acc[mt][1] = mfma16(al, b1l, acc[mt][1]);
        acc[mt][0] = mfma16(ah, b0h, acc[mt][0]);
        acc[mt][1] = mfma16(ah, b1h, acc[mt][1]);
      }
    }
  }
#pragma unroll
  for (int nt = 0; nt < 2; ++nt) {
    int e = eb + w * 32 + nt * 16 + m16;
    float bias = cb[e];
#pragma unroll
    for (int mt = 0; mt < 15; ++mt)
#pragma unroll
      for (int r = 0; r < 4; ++r) {
        int p = mt * 16 + g4 * 4 + r;
        xem[((size_t)(b * 240 + p)) * 512 + e] = acc[mt][nt][r] + bias;
      }
  }
}

// ---------------- attention scores: e[b][hw] ----------------
__global__ __launch_bounds__(256) void k_escore(
    const float* __restrict__ xem, const float* __restrict__ gem,
    const float* __restrict__ wv, const float* __restrict__ bv,
    float* __restrict__ esc)   // [64][240]
{
  int b = blockIdx.x >> 2, slice = blockIdx.x & 3;
  __shared__ float gl[512], wl[512];
  for (int i = threadIdx.x; i < 512; i += 256) { gl[i] = gem[b * 512 + i]; wl[i] = wv[i]; }
  __syncthreads();
  int lane = threadIdx.x & 63, wid = threadIdx.x >> 6;
  float bv0 = bv[0];
  for (int ii = 0; ii < 15; ++ii) {
    int hw = slice * 60 + wid * 15 + ii;
    const float* row = xem + ((size_t)(b * 240 + hw)) * 512;
    float s = 0.f;
#pragma unroll
    for (int cc = 0; cc < 8; ++cc) {
      int e = lane + cc * 64;
      s += tanh_(row[e] + gl[e]) * wl[e];
    }
#pragma unroll
    for (int m = 32; m; m >>= 1) s += __shfl_xor(s, m);
    if (lane == 0) esc[b * 240 + hw] = s + bv0;
  }
}

// ---------------- softmax over hw + context att[b][f] ----------------
__global__ __launch_bounds__(256) void k_attsm(
    const float* __restrict__ esc, const float* __restrict__ cf,
    float* __restrict__ att)   // [64][512]
{
  int b = blockIdx.x, t = threadIdx.x;
  __shared__ float sm[256];
  __shared__ float alpha[240];
  float v = (t < 240) ? esc[b * 240 + t] : -1e30f;
  sm[t] = v; __syncthreads();
  for (int s = 128; s; s >>= 1) { if (t < s) sm[t] = fmaxf(sm[t], sm[t + s]); __syncthreads(); }
  float mx = sm[0]; __syncthreads();
  float ex = (t < 240) ? __expf(v - mx) : 0.f;
  sm[t] = ex; __syncthreads();
  for (int s = 128; s; s >>= 1) { if (t < s) sm[t] += sm[t + s]; __syncthreads(); }
  float inv = 1.f / sm[0];
  if (t < 240) alpha[t] = ex * inv;
  __syncthreads();
  for (int f = t; f < 512; f += 256) {
    const float4* r4 = (const float4*)(cf + ((size_t)b * 512 + f) * 240);
    float a = 0.f;
#pragma unroll 4
    for (int q = 0; q < 60; ++q) {
      float4 vv = r4[q];
      a += alpha[q * 4] * vv.x + alpha[q * 4 + 1] * vv.y + alpha[q * 4 + 2] * vv.z + alpha[q * 4 + 3] * vv.w;
    }
    att[b * 512 + f] = a;
  }
}

// ---------------- logits + log_softmax + per-(b,t) NLL ----------------
__global__ __launch_bounds__(128) void k_logits(
    const f16* __restrict__ hlast, const float* __restrict__ att,
    const float* __restrict__ outw, const float* __restrict__ outb,
    const int* __restrict__ lt, int tstep, float* __restrict__ nll)   // nll[32][64]
{
  int b = blockIdx.x, t = threadIdx.x;
  __shared__ float ctx[1024];
  __shared__ float red[128];
  __shared__ float lgv[96];
  for (int i = t; i < 512; i += 128) {
    ctx[i] = (float)hlast[b * 512 + i];
    ctx[512 + i] = att[b * 512 + i];
  }
  __syncthreads();
  float val = -1e30f;
  if (t < 96) {
    const float4* w4 = (const float4*)(outw + (size_t)t * 1024);
    const float4* c4 = (const float4*)ctx;
    float s = outb[t];
#pragma unroll 4
    for (int q = 0; q < 256; ++q) {
      float4 a = c4[q], w = w4[q];
      s += a.x * w.x + a.y * w.y + a.z * w.z + a.w * w.w;
    }
    val = s;
    lgv[t] = s;
  }
  red[t] = val; __syncthreads();
  for (int s2 = 64; s2; s2 >>= 1) { if (t < s2) red[t] = fmaxf(red[t], red[t + s2]); __syncthreads(); }
  float mx = red[0]; __syncthreads();
  float ex = (t < 96) ? __expf(val - mx) : 0.f;
  red[t] = ex; __syncthreads();
  for (int s2 = 64; s2; s2 >>= 1) { if (t < s2) red[t] += red[t + s2]; __syncthreads(); }
  if (t == 0) {
    float lse = mx + __logf(red[0]);
    int tok = lt[b * 32 + tstep];
    nll[tstep * 64 + b] = (tok != 0) ? (lse - lgv[tok]) : 0.f;
  }
}

__global__ void k_loss(const float* __restrict__ nll, const int* __restrict__ ltg,
                       float* __restrict__ out) {
  __shared__ float sa[256], sb[256];
  int t = threadIdx.x;
  float a = 0.f, m = 0.f;
  for (int i = t; i < 2048; i += 256) {
    a += nll[i];
    m += (ltg[i] != 0) ? 1.f : 0.f;
  }
  sa[t] = a; sb[t] = m; __syncthreads();
  for (int s = 128; s; s >>= 1) { if (t < s) { sa[t] += sa[t + s]; sb[t] += sb[t + s]; } __syncthreads(); }
  if (t == 0) out[0] = sa[0] / sb[0];
}

// ---------------- host ----------------

extern "C" void kernel_launch(void* const* d_in, const int* in_sizes, int n_in,
                              void* d_out, int out_size, void* d_ws, size_t ws_size,
                              hipStream_t stream) {
  (void)in_sizes; (void)n_in; (void)out_size; (void)ws_size;
  const float* conv_f = (const float*)d_in[0];
  const int*   target = (const int*)d_in[1];
  const float* wih_en = (const float*)d_in[2];
  const float* whh_en = (const float*)d_in[3];
  const float* bih_en = (const float*)d_in[4];
  const float* bhh_en = (const float*)d_in[5];
  const float* embed  = (const float*)d_in[6];
  const float* wih_de = (const float*)d_in[7];
  const float* whh_de = (const float*)d_in[8];
  const float* bih_de = (const float*)d_in[9];
  const float* bhh_de = (const float*)d_in[10];
  const float* att_wh = (const float*)d_in[11];
  const float* att_bh = (const float*)d_in[12];
  const float* att_cw = (const float*)d_in[13];
  const float* att_cb = (const float*)d_in[14];
  const float* att_wv = (const float*)d_in[15];
  const float* att_bv = (const float*)d_in[16];
  const float* out_w  = (const float*)d_in[17];
  const float* out_b  = (const float*)d_in[18];
  float* out = (float*)d_out;

  size_t o = 0;
  char* base = (char*)d_ws;
  auto take = [&](size_t bytes) -> void* {
    void* p = base + o;
    o += (bytes + 255) & ~(size_t)255;
    return p;
  };
  f16* wihEn = (f16*)take((size_t)2 * 2048 * 512 * 2);
  f16* whhEn = (f16*)take((size_t)2 * 2048 * 512 * 2);
  f16* wihDe = (f16*)take((size_t)2 * 2048 * 512 * 2);
  f16* whhDe = (f16*)take((size_t)2 * 2048 * 512 * 2);
  f16* awh   = (f16*)take((size_t)512 * 512 * 2);
  f16* emb   = (f16*)take((size_t)96 * 512 * 2);
  f16* wc9   = (f16*)take((size_t)512 * 4608 * 2);
  f16* cfT   = (f16*)take((size_t)64 * 240 * 512 * 2);
  f16* xseq  = (f16*)take((size_t)40 * 64 * 512 * 2);
  f16* xs    = (f16*)take((size_t)32 * 64 * 512 * 2);
  float* xem = (float*)take((size_t)64 * 240 * 512 * 4);
  // zero-init state block: 8 x 131072 bytes contiguous
  f16* hEn0 = (f16*)take(131072);   // [2][64][512] f16 (ping-pong)
  f16* hEn1 = (f16*)take(131072);
  f16* hDe0 = (f16*)take(131072);
  f16* hDe1 = (f16*)take(131072);
  float* cEn0 = (float*)take(131072);  // [64][512] f32
  float* cEn1 = (float*)take(131072);
  float* cDe0 = (float*)take(131072);
  float* cDe1 = (float*)take(131072);
  float* gem  = (float*)take((size_t)64 * 512 * 4);
  float* esc  = (float*)take((size_t)64 * 240 * 4);
  float* attb = (float*)take((size_t)64 * 512 * 4);
  float* nllb = (float*)take((size_t)2048 * 4);
  int*   ltg  = (int*)take((size_t)2048 * 4);

  const int HB = 64 * 512;  // elements per [64][512] buffer

  // prologue
  k_convert4<<<(2 * 2048 * 512 / 4 + 255) / 256, 256, 0, stream>>>(wih_en, wihEn, 2 * 2048 * 512 / 4);
  k_convert4<<<(2 * 2048 * 512 / 4 + 255) / 256, 256, 0, stream>>>(whh_en, whhEn, 2 * 2048 * 512 / 4);
  k_convert4<<<(2 * 2048 * 512 / 4 + 255) / 256, 256, 0, stream>>>(wih_de, wihDe, 2 * 2048 * 512 / 4);
  k_convert4<<<(2 * 2048 * 512 / 4 + 255) / 256, 256, 0, stream>>>(whh_de, whhDe, 2 * 2048 * 512 / 4);
  k_convert4<<<(512 * 512 / 4 + 255) / 256, 256, 0, stream>>>(att_wh, awh, 512 * 512 / 4);
  k_convert4<<<(96 * 512 / 4 + 255) / 256, 256, 0, stream>>>(embed, emb, 96 * 512 / 4);
  k_wc9<<<(512 * 4608 + 255) / 256, 256, 0, stream>>>(att_cw, wc9);
  k_cfT<<<(64 * 240 * 512 + 255) / 256, 256, 0, stream>>>(conv_f, cfT);
  k_maxpool<<<(40 * 64 * 512 + 255) / 256, 256, 0, stream>>>(conv_f, xseq);
  k_ltarget<<<1, 64, 0, stream>>>(target, ltg);
  hipMemsetAsync(hEn0, 0, (size_t)8 * 131072, stream);

  k_conv<<<dim3(4, 64), 256, 0, stream>>>(cfT, wc9, att_cb, xem);

  // encoder
  for (int t = 0; t < 40; ++t) {
    int pi = t & 1, po = pi ^ 1;
    k_lstm_step<<<32, 256, 0, stream>>>(xseq + (size_t)t * HB, hEn0 + (size_t)pi * HB,
                                        wihEn, whhEn, bih_en, bhh_en, cEn0, hEn0 + (size_t)po * HB);
    k_lstm_step<<<32, 256, 0, stream>>>(hEn0 + (size_t)po * HB, hEn1 + (size_t)pi * HB,
                                        wihEn + (size_t)2048 * 512, whhEn + (size_t)2048 * 512,
                                        bih_en + 2048, bhh_en + 2048, cEn1, hEn1 + (size_t)po * HB);
  }
  // holistic = hEn1 buffer 0 (after 40 steps)
  k_fill_xs<<<(32 * 64 * 512 + 255) / 256, 256, 0, stream>>>(hEn1, emb, target, xs);

  // decoder
  for (int t = 0; t < 32; ++t) {
    int pi = t & 1, po = pi ^ 1;
    k_lstm_step<<<32, 256, 0, stream>>>(xs + (size_t)t * HB, hDe0 + (size_t)pi * HB,
                                        wihDe, whhDe, bih_de, bhh_de, cDe0, hDe0 + (size_t)po * HB);
    k_lstm_step<<<32, 256, 0, stream>>>(hDe0 + (size_t)po * HB, hDe1 + (size_t)pi * HB,
                                        wihDe + (size_t)2048 * 512, whhDe + (size_t)2048 * 512,
                                        bih_de + 2048, bhh_de + 2048, cDe1, hDe1 + (size_t)po * HB);
    const f16* hlast = hDe1 + (size_t)po * HB;
    k_gemm64<<<8, 256, 0, stream>>>(hlast, awh, att_bh, gem);
    k_escore<<<256, 256, 0, stream>>>(xem, gem, att_wv, att_bv, esc);
    k_attsm<<<64, 256, 0, stream>>>(esc, conv_f, attb);
    k_logits<<<64, 128, 0, stream>>>(hlast, attb, out_w, out_b, ltg, t, nllb);
  }
  k_loss<<<1, 256, 0, stream>>>(nllb, ltg, out);
}

// Round 2
// 3089.156 us; speedup vs baseline: 1.3721x; 1.3721x over previous
//
#include <hip/hip_runtime.h>

typedef __fp16 f16;
typedef __fp16 f16x4 __attribute__((ext_vector_type(4)));
typedef __fp16 f16x8 __attribute__((ext_vector_type(8)));
typedef float  f32x4 __attribute__((ext_vector_type(4)));

#define DEV static __device__ __forceinline__

DEV f32x4 mfma16(f16x4 a, f16x4 b, f32x4 c) {
  return __builtin_amdgcn_mfma_f32_16x16x16f16(a, b, c, 0, 0, 0);
}
DEV f16x4 lo4(f16x8 v) { return __builtin_shufflevector(v, v, 0, 1, 2, 3); }
DEV f16x4 hi4(f16x8 v) { return __builtin_shufflevector(v, v, 4, 5, 6, 7); }
DEV float sigf(float x) { return 1.f / (1.f + __expf(-x)); }
DEV float tanh_(float x) { float e = __expf(2.f * x); return 1.f - 2.f / (e + 1.f); }

union U8 { float4 f4; float2 f2[2]; };

#define HB 32768   // elements in a [64][512] buffer
#define GB 32768

// k-permuted staging of 16 f16 (one row-chunk quarter) into a 72-stride LDS row
DEV void stageRow(const f16* __restrict__ s, f16* __restrict__ dstRow, int ch) {
  U8 u0, u1;
  u0.f4 = *(const float4*)s;
  u1.f4 = *(const float4*)(s + 8);
  *(float2*)(dstRow +  0 + ch * 4) = u0.f2[0];
  *(float2*)(dstRow + 16 + ch * 4) = u0.f2[1];
  *(float2*)(dstRow + 32 + ch * 4) = u1.f2[0];
  *(float2*)(dstRow + 48 + ch * 4) = u1.f2[1];
}

// stage full [64][512] A matrix into sA[8][64][72] (issue all loads first)
DEV void stageA(const f16* __restrict__ src, f16 (*A)[64][72], int tid) {
  int row = tid >> 2, ch = tid & 3;
  const f16* s = src + (size_t)row * 512 + ch * 16;
  U8 u[8][2];
#pragma unroll
  for (int c = 0; c < 8; ++c) {
    u[c][0].f4 = *(const float4*)(s + c * 64);
    u[c][1].f4 = *(const float4*)(s + c * 64 + 8);
  }
#pragma unroll
  for (int c = 0; c < 8; ++c) {
    f16* d = &A[c][row][0];
    *(float2*)(d +  0 + ch * 4) = u[c][0].f2[0];
    *(float2*)(d + 16 + ch * 4) = u[c][0].f2[1];
    *(float2*)(d + 32 + ch * 4) = u[c][1].f2[0];
    *(float2*)(d + 48 + ch * 4) = u[c][1].f2[1];
  }
}

// 64x32 output tile: wave (mh,ns); acc[2] f32x4
DEV void kloop32(const f16 (*Wt)[32][72], const f16 (*A)[64][72],
                 int mh, int ns, int m16, int g4, f32x4 acc[2]) {
#pragma unroll
  for (int c = 0; c < 8; ++c) {
#pragma unroll
    for (int half = 0; half < 2; ++half) {
      f16x8 bf = *(const f16x8*)&Wt[c][ns * 16 + m16][g4 * 16 + half * 8];
      f16x4 bl = lo4(bf), bh = hi4(bf);
#pragma unroll
      for (int mt = 0; mt < 2; ++mt) {
        f16x8 af = *(const f16x8*)&A[c][mh * 32 + mt * 16 + m16][g4 * 16 + half * 8];
        acc[mt] = mfma16(lo4(af), bl, acc[mt]);
        acc[mt] = mfma16(hi4(af), bh, acc[mt]);
      }
    }
  }
}

// 64x64 output tile (GEM role): wave = n-quarter; acc[4]
DEV void kloop64(const f16* Wg, const f16 (*A)[64][72],
                 int nsG, int m16, int g4, f32x4 acc[4]) {
#pragma unroll
  for (int c = 0; c < 8; ++c) {
#pragma unroll
    for (int half = 0; half < 2; ++half) {
      f16x8 bf = *(const f16x8*)&Wg[((size_t)(c * 64 + nsG * 16 + m16)) * 72 + g4 * 16 + half * 8];
      f16x4 bl = lo4(bf), bh = hi4(bf);
#pragma unroll
      for (int mt = 0; mt < 4; ++mt) {
        f16x8 af = *(const f16x8*)&A[c][mt * 16 + m16][g4 * 16 + half * 8];
        acc[mt] = mfma16(lo4(af), bl, acc[mt]);
        acc[mt] = mfma16(hi4(af), bh, acc[mt]);
      }
    }
  }
}

// device-scope grid barrier: 8 slot counters (bar[0..112 step16]) + flag bar[128]
DEV void gridbar(unsigned* bar, int nb, unsigned target) {
  __syncthreads();
  if (threadIdx.x == 0) {
    int slot = blockIdx.x & 7;
    __hip_atomic_fetch_add(&bar[slot * 16], 1u, __ATOMIC_RELEASE, __HIP_MEMORY_SCOPE_AGENT);
    if (blockIdx.x == 0) {
      unsigned per = (unsigned)(nb >> 3) * target;
      for (int s = 0; s < 8; ++s)
        while (__hip_atomic_load(&bar[s * 16], __ATOMIC_ACQUIRE, __HIP_MEMORY_SCOPE_AGENT) < per)
          __builtin_amdgcn_s_sleep(1);
      __hip_atomic_store(&bar[128], target, __ATOMIC_RELEASE, __HIP_MEMORY_SCOPE_AGENT);
    } else {
      while (__hip_atomic_load(&bar[128], __ATOMIC_RELAXED, __HIP_MEMORY_SCOPE_AGENT) < target)
        __builtin_amdgcn_s_sleep(8);
      (void)__hip_atomic_load(&bar[128], __ATOMIC_ACQUIRE, __HIP_MEMORY_SCOPE_AGENT);
    }
  }
  __syncthreads();
}

// ---------------- prologue kernels ----------------

__global__ void k_convert4(const float* __restrict__ src, f16* __restrict__ dst, int n4) {
  int i = blockIdx.x * 256 + threadIdx.x;
  if (i < n4) {
    float4 v = ((const float4*)src)[i];
    f16x4 o = { (f16)v.x, (f16)v.y, (f16)v.z, (f16)v.w };
    *(f16x4*)(dst + (size_t)i * 4) = o;
  }
}

__global__ void k_wc9(const float* __restrict__ src, f16* __restrict__ dst) {
  int i = blockIdx.x * 256 + threadIdx.x;
  if (i < 512 * 4608) {
    int e = i / 4608, k = i % 4608;
    int rr = k / 512, f = k % 512;
    dst[i] = (f16)src[(size_t)e * 4608 + f * 9 + rr];
  }
}

__global__ void k_cfT(const float* __restrict__ cf, f16* __restrict__ dst) {
  int i = blockIdx.x * 256 + threadIdx.x;
  if (i < 64 * 240 * 512) {
    int b = i / (240 * 512), r = i % (240 * 512);
    int p = r / 512, f = r % 512;
    dst[i] = (f16)cf[((size_t)b * 512 + f) * 240 + p];
  }
}

__global__ void k_maxpool(const float* __restrict__ cf, f16* __restrict__ xseq) {
  int i = blockIdx.x * 256 + threadIdx.x;
  if (i < 40 * 64 * 512) {
    int w = i / (64 * 512), r = i % (64 * 512);
    int b = r / 512, f = r % 512;
    const float* base = cf + ((size_t)b * 512 + f) * 240 + w;
    float m = base[0];
#pragma unroll
    for (int h = 1; h < 6; ++h) m = fmaxf(m, base[h * 40]);
    xseq[i] = (f16)m;
  }
}

__global__ void k_ltarget(const int* __restrict__ target, int* __restrict__ lt) {
  int b = threadIdx.x;
  if (b >= 64) return;
  int row[32];
  row[0] = 0;
  for (int t = 1; t <= 30; ++t) row[t] = target[b * 30 + t - 1];
  row[31] = 0;
  int j = 1;
  while (row[j] != 0) ++j;
  row[j] = 95;
  for (int t = 0; t < 32; ++t) lt[b * 32 + t] = row[t];
}

__global__ void k_fill_xs(const f16* __restrict__ hol, const f16* __restrict__ emb,
                          const int* __restrict__ tgt, f16* __restrict__ xs) {
  int i = blockIdx.x * 256 + threadIdx.x;
  if (i < 32 * 64 * 512) {
    int t = i / (64 * 512), r = i % (64 * 512);
    int b = r / 512, u = r % 512;
    f16 v;
    if (t == 0) v = hol[b * 512 + u];
    else {
      int tok = (t == 1) ? 95 : tgt[b * 30 + t - 2];
      v = emb[(size_t)tok * 512 + u];
    }
    xs[i] = v;
  }
}

// ---------------- batched X0 GEMM: C[M][2048] = A[M][512] @ W^T + b1 + b2 (f16 out) ----------------
__global__ __launch_bounds__(256) void k_gemmX(
    const f16* __restrict__ A, const f16* __restrict__ W,
    const float* __restrict__ b1, const float* __restrict__ b2,
    f16* __restrict__ C)
{
  __shared__ f16 At[64][72];
  __shared__ f16 Bt[64][72];
  const int t = threadIdx.x, lane = t & 63, g = t >> 6;
  f32x4 acc[4] = {};
  const int m16 = lane & 15, g4 = lane >> 4;
  const size_t arow0 = (size_t)blockIdx.x * 64;

  for (int k0 = 0; k0 < 512; k0 += 64) {
    __syncthreads();
    { int row = t >> 2, ch = t & 3;
      stageRow(A + (arow0 + row) * 512 + k0 + ch * 16, &At[row][0], ch); }
    { int row = t >> 2, ch = t & 3;
      stageRow(W + ((size_t)blockIdx.y * 64 + row) * 512 + k0 + ch * 16, &Bt[row][0], ch); }
    __syncthreads();
#pragma unroll
    for (int half = 0; half < 2; ++half) {
      f16x8 bf = *(const f16x8*)&Bt[g * 16 + m16][g4 * 16 + half * 8];
      f16x4 bl = lo4(bf), bh = hi4(bf);
#pragma unroll
      for (int mt = 0; mt < 4; ++mt) {
        f16x8 af = *(const f16x8*)&At[mt * 16 + m16][g4 * 16 + half * 8];
        acc[mt] = mfma16(lo4(af), bl, acc[mt]);
        acc[mt] = mfma16(hi4(af), bh, acc[mt]);
      }
    }
  }
  int e = blockIdx.y * 64 + g * 16 + m16;
  float bias = b1[e] + b2[e];
#pragma unroll
  for (int mt = 0; mt < 4; ++mt)
#pragma unroll
    for (int r = 0; r < 4; ++r)
      C[(arow0 + mt * 16 + g4 * 4 + r) * 2048 + e] = (f16)(acc[mt][r] + bias);
}

// ---------------- conv 3x3 as 9 shifted MFMA GEMMs (f16 out) ----------------
__global__ __launch_bounds__(256, 1) void k_conv(
    const f16* __restrict__ cfT, const f16* __restrict__ wc9,
    const float* __restrict__ cb, f16* __restrict__ xemH)
{
  __shared__ f16 At[240][40];
  __shared__ f16 Bt[128][40];
  const int t = threadIdx.x, lane = t & 63, w = t >> 6;
  const int b = blockIdx.y, eb = blockIdx.x * 128;
  const int m16 = lane & 15, g4 = lane >> 4;
  f32x4 acc[15][2] = {};

  for (int kr = 0; kr < 9; ++kr) {
    int dh = kr / 3 - 1, dw = kr % 3 - 1;
    for (int f0 = 0; f0 < 512; f0 += 32) {
      __syncthreads();
      if (t < 240) {
        int hh = t / 40 + dh, ww = t % 40 + dw;
        if (hh >= 0 && hh < 6 && ww >= 0 && ww < 40) {
          const f16* s = cfT + ((size_t)(b * 240 + hh * 40 + ww) * 512 + f0);
          U8 u0, u1, u2, u3;
          u0.f4 = *(const float4*)s;        u1.f4 = *(const float4*)(s + 8);
          u2.f4 = *(const float4*)(s + 16); u3.f4 = *(const float4*)(s + 24);
          *(float2*)&At[t][ 0] = u0.f2[0];
          *(float2*)&At[t][ 8] = u0.f2[1];
          *(float2*)&At[t][16] = u1.f2[0];
          *(float2*)&At[t][24] = u1.f2[1];
          *(float2*)&At[t][ 4] = u2.f2[0];
          *(float2*)&At[t][12] = u2.f2[1];
          *(float2*)&At[t][20] = u3.f2[0];
          *(float2*)&At[t][28] = u3.f2[1];
        } else {
          float2 z = make_float2(0.f, 0.f);
          *(float2*)&At[t][ 0] = z; *(float2*)&At[t][ 8] = z;
          *(float2*)&At[t][16] = z; *(float2*)&At[t][24] = z;
          *(float2*)&At[t][ 4] = z; *(float2*)&At[t][12] = z;
          *(float2*)&At[t][20] = z; *(float2*)&At[t][28] = z;
        }
      }
      {
        int n = t >> 1, ch = t & 1;
        const f16* s = wc9 + (size_t)(eb + n) * 4608 + kr * 512 + f0 + ch * 16;
        U8 u0, u1;
        u0.f4 = *(const float4*)s; u1.f4 = *(const float4*)(s + 8);
        *(float2*)&Bt[n][ 0 + ch * 4] = u0.f2[0];
        *(float2*)&Bt[n][ 8 + ch * 4] = u0.f2[1];
        *(float2*)&Bt[n][16 + ch * 4] = u1.f2[0];
        *(float2*)&Bt[n][24 + ch * 4] = u1.f2[1];
      }
      __syncthreads();
      f16x8 b0 = *(const f16x8*)&Bt[w * 32 + m16][g4 * 8];
      f16x8 b1v = *(const f16x8*)&Bt[w * 32 + 16 + m16][g4 * 8];
      f16x4 b0l = lo4(b0), b0h = hi4(b0), b1l = lo4(b1v), b1h = hi4(b1v);
#pragma unroll
      for (int mt = 0; mt < 15; ++mt) {
        f16x8 af = *(const f16x8*)&At[mt * 16 + m16][g4 * 8];
        f16x4 al = lo4(af), ah = hi4(af);
        acc[mt][0] = mfma16(al, b0l, acc[mt][0]);
        acc[mt][1] = mfma16(al, b1l, acc[mt][1]);
        acc[mt][0] = mfma16(ah, b0h, acc[mt][0]);
        acc[mt][1] = mfma16(ah, b1h, acc[mt][1]);
      }
    }
  }
#pragma unroll
  for (int nt = 0; nt < 2; ++nt) {
    int e = eb + w * 32 + nt * 16 + m16;
    float bias = cb[e];
#pragma unroll
    for (int mt = 0; mt < 15; ++mt)
#pragma unroll
      for (int r = 0; r < 4; ++r) {
        int p = mt * 16 + g4 * 4 + r;
        xemH[((size_t)(b * 240 + p)) * 512 + e] = (f16)(acc[mt][nt][r] + bias);
      }
  }
}

// ---------------- persistent encoder ----------------
__global__ __launch_bounds__(256, 1) void k_enc(
    const f16* __restrict__ G0,
    const f16* __restrict__ whh0,
    const f16* __restrict__ wih1, const f16* __restrict__ whh1,
    const float* __restrict__ bih1, const float* __restrict__ bhh1,
    f16* __restrict__ h0pp, f16* __restrict__ h1pp,
    unsigned* __restrict__ bar)
{
  __shared__ f16 sW[2][8][32][72];
  __shared__ f16 sA[8][64][72];
  float* sG = (float*)sA;   // [4][64][9]
  const int tid = threadIdx.x, lane = tid & 63, w = tid >> 6;
  const int bid = blockIdx.x;
  const int role = bid >> 6, utile = bid & 63;
  const int m16 = lane & 15, g4 = lane >> 4;
  const int mh = w >> 1, ns = w & 1;

  { // stage weight tiles once
    int mat = tid >> 7;
    int r = (tid >> 2) & 31, ch = tid & 3;
    int grow = (r >> 3) * 512 + utile * 8 + (r & 7);
    const f16* Wsrc = (role == 0) ? (mat == 0 ? whh0 : (const f16*)nullptr)
                                  : (mat == 0 ? wih1 : whh1);
    if (Wsrc) {
      for (int c = 0; c < 8; ++c)
        stageRow(Wsrc + (size_t)grow * 512 + c * 64 + ch * 16, &sW[mat][c][r][0], ch);
    }
  }
  float badd[4] = {};
  if (role == 1) {
    int ul = tid & 7;
#pragma unroll
    for (int g = 0; g < 4; ++g) {
      int rr = g * 512 + utile * 8 + ul;
      badd[g] = bih1[rr] + bhh1[rr];
    }
  }
  float cst[2] = {0.f, 0.f};

  for (int s = 0; s <= 40; ++s) {
    bool act = (role == 0) ? (s < 40) : (s >= 1);
    if (act) {
      int t = (role == 0) ? s : s - 1;
      f32x4 acc[2] = {};
      if (role == 0) {
        stageA(h0pp + (size_t)(s & 1) * HB, sA, tid);
        __syncthreads();
        kloop32(sW[0], sA, mh, ns, m16, g4, acc);
        __syncthreads();
      } else {
        stageA(h0pp + (size_t)(s & 1) * HB, sA, tid);       // h0[t]
        __syncthreads();
        kloop32(sW[0], sA, mh, ns, m16, g4, acc);           // Wih1
        __syncthreads();
        stageA(h1pp + (size_t)((s - 1) & 1) * HB, sA, tid); // h1[t-1]
        __syncthreads();
        kloop32(sW[1], sA, mh, ns, m16, g4, acc);           // Whh1
        __syncthreads();
      }
      { // gates -> LDS
        int nl = ns * 16 + m16;
#pragma unroll
        for (int mt = 0; mt < 2; ++mt)
#pragma unroll
          for (int r = 0; r < 4; ++r) {
            int b = mh * 32 + mt * 16 + g4 * 4 + r;
            sG[((nl >> 3) * 64 + b) * 9 + (nl & 7)] = acc[mt][r];
          }
      }
      __syncthreads();
      f16* hout = (role == 0) ? h0pp + (size_t)((s + 1) & 1) * HB
                              : h1pp + (size_t)(s & 1) * HB;
#pragma unroll
      for (int oi = 0; oi < 2; ++oi) {
        int idx = tid + oi * 256;
        int b = idx >> 3, ul = idx & 7;
        float gi = sG[(0 * 64 + b) * 9 + ul], gf = sG[(1 * 64 + b) * 9 + ul],
              gg = sG[(2 * 64 + b) * 9 + ul], go = sG[(3 * 64 + b) * 9 + ul];
        if (role == 0) {
          const f16* gp = G0 + ((size_t)(t * 64 + b)) * 2048 + utile * 8 + ul;
          gi += (float)gp[0]; gf += (float)gp[512]; gg += (float)gp[1024]; go += (float)gp[1536];
        } else {
          gi += badd[0]; gf += badd[1]; gg += badd[2]; go += badd[3];
        }
        float cn = sigf(gf) * cst[oi] + sigf(gi) * tanh_(gg);
        float hn = sigf(go) * tanh_(cn);
        cst[oi] = cn;
        hout[b * 512 + utile * 8 + ul] = (f16)hn;
      }
    }
    gridbar(bar, 128, (unsigned)(s + 1));
  }
}

// ---------------- persistent decoder ----------------
__global__ __launch_bounds__(256, 1) void k_dec(
    const f16* __restrict__ G0,
    const f16* __restrict__ whh0,
    const f16* __restrict__ wih1, const f16* __restrict__ whh1,
    const float* __restrict__ bih1, const float* __restrict__ bhh1,
    f16* __restrict__ h0pp, f16* __restrict__ h1seq,
    const f16* __restrict__ awh, const float* __restrict__ gbias,
    float* __restrict__ gempp,
    const f16* __restrict__ xemH, const f16* __restrict__ cfH,
    const float* __restrict__ wv, const float* __restrict__ bv,
    const f16* __restrict__ outwH, const float* __restrict__ outb,
    const int* __restrict__ ltg, float* __restrict__ nll,
    unsigned* __restrict__ bar)
{
  __shared__ f16 sW[2][8][32][72];
  __shared__ f16 sA[8][64][72];
  float* sG = (float*)sA;
  const int tid = threadIdx.x, lane = tid & 63, w = tid >> 6;
  const int bid = blockIdx.x;
  const int role = (bid < 64) ? 0 : (bid < 128) ? 1 : (bid < 136) ? 2 : 3;
  const int utile = bid & 63;          // L0/L1
  const int gtile = bid - 128;         // GEM
  const int ab = bid - 136;            // ATT batch
  const int m16 = lane & 15, g4 = lane >> 4;
  const int mh = w >> 1, ns = w & 1;

  // per-role one-time setup
  if (role <= 1) {
    int mat = tid >> 7;
    int r = (tid >> 2) & 31, ch = tid & 3;
    int grow = (r >> 3) * 512 + utile * 8 + (r & 7);
    const f16* Wsrc = (role == 0) ? (mat == 0 ? whh0 : (const f16*)nullptr)
                                  : (mat == 0 ? wih1 : whh1);
    if (Wsrc) {
      for (int c = 0; c < 8; ++c)
        stageRow(Wsrc + (size_t)grow * 512 + c * 64 + ch * 16, &sW[mat][c][r][0], ch);
    }
  } else if (role == 2) {
    f16* sWg = (f16*)sW;   // [8][64][72]
    int r = tid >> 2, ch = tid & 3;
    for (int c = 0; c < 8; ++c)
      stageRow(awh + (size_t)(gtile * 64 + r) * 512 + c * 64 + ch * 16,
               sWg + ((size_t)(c * 64 + r)) * 72, ch);
  }
  float badd[4] = {};
  if (role == 1) {
    int ul = tid & 7;
#pragma unroll
    for (int g = 0; g < 4; ++g) {
      int rr = g * 512 + utile * 8 + ul;
      badd[g] = bih1[rr] + bhh1[rr];
    }
  }
  float gbias_r = 0.f;
  if (role == 2) gbias_r = gbias[gtile * 64 + w * 16 + m16];
  float w8[8];
  float ob = 0.f, bv0 = 0.f;
  if (role == 3) {
    const float4* wp = (const float4*)(wv + lane * 8);
    float4 wa = wp[0], wb = wp[1];
    w8[0] = wa.x; w8[1] = wa.y; w8[2] = wa.z; w8[3] = wa.w;
    w8[4] = wb.x; w8[5] = wb.y; w8[6] = wb.z; w8[7] = wb.w;
    if (tid < 96) ob = outb[tid];
    bv0 = bv[0];
  }
  float cst[2] = {0.f, 0.f};

  float* aCtx = (float*)sA;       // [1024]
  float* aE   = aCtx + 1024;      // [256] scores -> alpha
  float* aRed = aE + 256;         // [256]
  float* aLog = aRed + 256;       // [96]

  for (int s = 0; s <= 34; ++s) {
    if (role == 0 && s < 32) {
      int t = s;
      f32x4 acc[2] = {};
      stageA(h0pp + (size_t)(s & 1) * HB, sA, tid);
      __syncthreads();
      kloop32(sW[0], sA, mh, ns, m16, g4, acc);
      __syncthreads();
      int nl = ns * 16 + m16;
#pragma unroll
      for (int mt = 0; mt < 2; ++mt)
#pragma unroll
        for (int r = 0; r < 4; ++r) {
          int b = mh * 32 + mt * 16 + g4 * 4 + r;
          sG[((nl >> 3) * 64 + b) * 9 + (nl & 7)] = acc[mt][r];
        }
      __syncthreads();
      f16* hout = h0pp + (size_t)((s + 1) & 1) * HB;
#pragma unroll
      for (int oi = 0; oi < 2; ++oi) {
        int idx = tid + oi * 256;
        int b = idx >> 3, ul = idx & 7;
        float gi = sG[(0 * 64 + b) * 9 + ul], gf = sG[(1 * 64 + b) * 9 + ul],
              gg = sG[(2 * 64 + b) * 9 + ul], go = sG[(3 * 64 + b) * 9 + ul];
        const f16* gp = G0 + ((size_t)(t * 64 + b)) * 2048 + utile * 8 + ul;
        gi += (float)gp[0]; gf += (float)gp[512]; gg += (float)gp[1024]; go += (float)gp[1536];
        float cn = sigf(gf) * cst[oi] + sigf(gi) * tanh_(gg);
        float hn = sigf(go) * tanh_(cn);
        cst[oi] = cn;
        hout[b * 512 + utile * 8 + ul] = (f16)hn;
      }
    } else if (role == 1 && s >= 1 && s <= 32) {
      int t = s - 1;
      f32x4 acc[2] = {};
      stageA(h0pp + (size_t)(s & 1) * HB, sA, tid);             // h0[t]
      __syncthreads();
      kloop32(sW[0], sA, mh, ns, m16, g4, acc);
      __syncthreads();
      stageA(h1seq + (size_t)(s - 1) * HB, sA, tid);            // h1[t-1]
      __syncthreads();
      kloop32(sW[1], sA, mh, ns, m16, g4, acc);
      __syncthreads();
      int nl = ns * 16 + m16;
#pragma unroll
      for (int mt = 0; mt < 2; ++mt)
#pragma unroll
        for (int r = 0; r < 4; ++r) {
          int b = mh * 32 + mt * 16 + g4 * 4 + r;
          sG[((nl >> 3) * 64 + b) * 9 + (nl & 7)] = acc[mt][r];
        }
      __syncthreads();
      f16* hout = h1seq + (size_t)s * HB;                       // slot t+1
#pragma unroll
      for (int oi = 0; oi < 2; ++oi) {
        int idx = tid + oi * 256;
        int b = idx >> 3, ul = idx & 7;
        float gi = sG[(0 * 64 + b) * 9 + ul] + badd[0], gf = sG[(1 * 64 + b) * 9 + ul] + badd[1],
              gg = sG[(2 * 64 + b) * 9 + ul] + badd[2], go = sG[(3 * 64 + b) * 9 + ul] + badd[3];
        float cn = sigf(gf) * cst[oi] + sigf(gi) * tanh_(gg);
        float hn = sigf(go) * tanh_(cn);
        cst[oi] = cn;
        hout[b * 512 + utile * 8 + ul] = (f16)hn;
      }
    } else if (role == 2 && s >= 2 && s <= 33) {
      int t = s - 2;
      f32x4 acc[4] = {};
      stageA(h1seq + (size_t)(s - 1) * HB, sA, tid);            // h1[t]
      __syncthreads();
      kloop64((const f16*)sW, sA, w, m16, g4, acc);
      __syncthreads();
      float* gout = gempp + (size_t)(t & 1) * GB;
      int e = gtile * 64 + w * 16 + m16;
#pragma unroll
      for (int mt = 0; mt < 4; ++mt)
#pragma unroll
        for (int r = 0; r < 4; ++r)
          gout[(mt * 16 + g4 * 4 + r) * 512 + e] = acc[mt][r] + gbias_r;
    } else if (role == 3 && s >= 3) {
      int t = s - 3;
      // phase0: gem into regs, h1 ctx into LDS
      float g8[8];
      {
        const float4* gp = (const float4*)(gempp + (size_t)(t & 1) * GB + ab * 512 + lane * 8);
        float4 ga = gp[0], gb4 = gp[1];
        g8[0] = ga.x; g8[1] = ga.y; g8[2] = ga.z; g8[3] = ga.w;
        g8[4] = gb4.x; g8[5] = gb4.y; g8[6] = gb4.z; g8[7] = gb4.w;
        const f16* h1t = h1seq + (size_t)(t + 1) * HB + ab * 512;
        for (int i = tid; i < 512; i += 256) aCtx[i] = (float)h1t[i];
      }
      __syncthreads();
      // escore: wave per row
      for (int r = w; r < 240; r += 4) {
        f16x8 xv = *(const f16x8*)(xemH + ((size_t)(ab * 240 + r)) * 512 + lane * 8);
        float ssum = 0.f;
#pragma unroll
        for (int j = 0; j < 8; ++j)
          ssum += tanh_((float)xv[j] + g8[j]) * w8[j];
#pragma unroll
        for (int m = 32; m; m >>= 1) ssum += __shfl_xor(ssum, m);
        if (lane == 0) aE[r] = ssum + bv0;
      }
      __syncthreads();
      // softmax over 240
      float v = (tid < 240) ? aE[tid] : -1e30f;
      aRed[tid] = v; __syncthreads();
      for (int st = 128; st; st >>= 1) { if (tid < st) aRed[tid] = fmaxf(aRed[tid], aRed[tid + st]); __syncthreads(); }
      float mx = aRed[0]; __syncthreads();
      float ex = (tid < 240) ? __expf(v - mx) : 0.f;
      aRed[tid] = ex; __syncthreads();
      for (int st = 128; st; st >>= 1) { if (tid < st) aRed[tid] += aRed[tid + st]; __syncthreads(); }
      float inv = 1.f / aRed[0];
      __syncthreads();
      if (tid < 240) aE[tid] = ex * inv;
      __syncthreads();
      // context
      for (int f = tid; f < 512; f += 256) {
        const f16* cr = cfH + ((size_t)(ab * 512 + f)) * 240;
        float a = 0.f;
#pragma unroll 2
        for (int q = 0; q < 30; ++q) {
          f16x8 cv = *(const f16x8*)(cr + q * 8);
#pragma unroll
          for (int j = 0; j < 8; ++j) a += aE[q * 8 + j] * (float)cv[j];
        }
        aCtx[512 + f] = a;
      }
      __syncthreads();
      // logits: 192 threads, half-rows
      if (tid < 192) {
        int r = tid >> 1, hh = tid & 1;
        const f16* wr = outwH + (size_t)r * 1024 + hh * 512;
        const float* cx = aCtx + hh * 512;
        float sdot = 0.f;
        for (int q = 0; q < 64; ++q) {
          f16x8 wv8 = *(const f16x8*)(wr + q * 8);
#pragma unroll
          for (int j = 0; j < 8; ++j) sdot += cx[q * 8 + j] * (float)wv8[j];
        }
        aRed[tid] = sdot;
      }
      __syncthreads();
      if (tid < 96) aLog[tid] = aRed[tid * 2] + aRed[tid * 2 + 1] + ob;
      __syncthreads();
      float lv = (tid < 96) ? aLog[tid] : -1e30f;
      aRed[tid] = lv; __syncthreads();
      for (int st = 128; st; st >>= 1) { if (tid < st) aRed[tid] = fmaxf(aRed[tid], aRed[tid + st]); __syncthreads(); }
      float mx2 = aRed[0]; __syncthreads();
      aRed[tid] = (tid < 96) ? __expf(lv - mx2) : 0.f;
      __syncthreads();
      for (int st = 128; st; st >>= 1) { if (tid < st) aRed[tid] += aRed[tid + st]; __syncthreads(); }
      if (tid == 0) {
        float lse = mx2 + __logf(aRed[0]);
        int tok = ltg[ab * 32 + t];
        nll[t * 64 + ab] = (tok != 0) ? (lse - aLog[tok]) : 0.f;
      }
    }
    gridbar(bar, 200, (unsigned)(s + 1));
  }
}

__global__ void k_loss(const float* __restrict__ nll, const int* __restrict__ ltg,
                       float* __restrict__ out) {
  __shared__ float sa[256], sb[256];
  int t = threadIdx.x;
  float a = 0.f, m = 0.f;
  for (int i = t; i < 2048; i += 256) {
    a += nll[i];
    m += (ltg[i] != 0) ? 1.f : 0.f;
  }
  sa[t] = a; sb[t] = m; __syncthreads();
  for (int s = 128; s; s >>= 1) { if (t < s) { sa[t] += sa[t + s]; sb[t] += sb[t + s]; } __syncthreads(); }
  if (t == 0) out[0] = sa[0] / sb[0];
}

// ---------------- host ----------------

extern "C" void kernel_launch(void* const* d_in, const int* in_sizes, int n_in,
                              void* d_out, int out_size, void* d_ws, size_t ws_size,
                              hipStream_t stream) {
  (void)in_sizes; (void)n_in; (void)out_size; (void)ws_size;
  const float* conv_f = (const float*)d_in[0];
  const int*   target = (const int*)d_in[1];
  const float* wih_en = (const float*)d_in[2];
  const float* whh_en = (const float*)d_in[3];
  const float* bih_en = (const float*)d_in[4];
  const float* bhh_en = (const float*)d_in[5];
  const float* embed  = (const float*)d_in[6];
  const float* wih_de = (const float*)d_in[7];
  const float* whh_de = (const float*)d_in[8];
  const float* bih_de = (const float*)d_in[9];
  const float* bhh_de = (const float*)d_in[10];
  const float* att_wh = (const float*)d_in[11];
  const float* att_bh = (const float*)d_in[12];
  const float* att_cw = (const float*)d_in[13];
  const float* att_cb = (const float*)d_in[14];
  const float* att_wv = (const float*)d_in[15];
  const float* att_bv = (const float*)d_in[16];
  const float* out_w  = (const float*)d_in[17];
  const float* out_b  = (const float*)d_in[18];
  float* out = (float*)d_out;

  size_t o = 0;
  char* base = (char*)d_ws;
  auto take = [&](size_t bytes) -> void* {
    void* p = base + o;
    o += (bytes + 255) & ~(size_t)255;
    return p;
  };
  const size_t WSZ = (size_t)2048 * 512;   // per layer-matrix elements
  f16* wihEn = (f16*)take(2 * WSZ * 2);
  f16* whhEn = (f16*)take(2 * WSZ * 2);
  f16* wihDe = (f16*)take(2 * WSZ * 2);
  f16* whhDe = (f16*)take(2 * WSZ * 2);
  f16* awh   = (f16*)take((size_t)512 * 512 * 2);
  f16* emb   = (f16*)take((size_t)96 * 512 * 2);
  f16* wc9   = (f16*)take((size_t)512 * 4608 * 2);
  f16* cfT   = (f16*)take((size_t)64 * 240 * 512 * 2);
  f16* xseq  = (f16*)take((size_t)40 * 64 * 512 * 2);
  f16* xs    = (f16*)take((size_t)32 * 64 * 512 * 2);
  f16* xemH  = (f16*)take((size_t)64 * 240 * 512 * 2);
  f16* cfH   = (f16*)take((size_t)64 * 512 * 240 * 2);
  f16* outwH = (f16*)take((size_t)96 * 1024 * 2);
  f16* X0en  = (f16*)take((size_t)2560 * 2048 * 2);
  f16* X0de  = (f16*)take((size_t)2048 * 2048 * 2);
  f16* hstate = (f16*)take((size_t)6 * HB * 2);        // h0ppE[2] h1ppE[2] h0ppD[2]
  f16* h0ppE = hstate;
  f16* h1ppE = hstate + 2 * HB;
  f16* h0ppD = hstate + 4 * HB;
  f16* h1seq = (f16*)take((size_t)33 * HB * 2);
  float* gempp = (float*)take((size_t)2 * GB * 4);
  float* nllb  = (float*)take((size_t)2048 * 4);
  int*   ltg   = (int*)take((size_t)2048 * 4);
  unsigned* barE = (unsigned*)take(1024);
  unsigned* barD = (unsigned*)take(1024);

  // prologue conversions
  k_convert4<<<2048, 256, 0, stream>>>(wih_en, wihEn, (int)(2 * WSZ / 4));
  k_convert4<<<2048, 256, 0, stream>>>(whh_en, whhEn, (int)(2 * WSZ / 4));
  k_convert4<<<2048, 256, 0, stream>>>(wih_de, wihDe, (int)(2 * WSZ / 4));
  k_convert4<<<2048, 256, 0, stream>>>(whh_de, whhDe, (int)(2 * WSZ / 4));
  k_convert4<<<256, 256, 0, stream>>>(att_wh, awh, 512 * 512 / 4);
  k_convert4<<<48, 256, 0, stream>>>(embed, emb, 96 * 512 / 4);
  k_convert4<<<7680, 256, 0, stream>>>(conv_f, cfH, 64 * 512 * 240 / 4);
  k_convert4<<<96, 256, 0, stream>>>(out_w, outwH, 96 * 1024 / 4);
  k_wc9<<<(512 * 4608 + 255) / 256, 256, 0, stream>>>(att_cw, wc9);
  k_cfT<<<(64 * 240 * 512 + 255) / 256, 256, 0, stream>>>(conv_f, cfT);
  k_maxpool<<<(40 * 64 * 512 + 255) / 256, 256, 0, stream>>>(conv_f, xseq);
  k_ltarget<<<1, 64, 0, stream>>>(target, ltg);
  hipMemsetAsync(hstate, 0, (size_t)6 * HB * 2, stream);
  hipMemsetAsync(h1seq, 0, (size_t)HB * 2, stream);   // slot 0
  hipMemsetAsync(barE, 0, 2048, stream);              // barE + barD contiguous

  k_conv<<<dim3(4, 64), 256, 0, stream>>>(cfT, wc9, att_cb, xemH);

  // batched layer-0 input GEMMs
  k_gemmX<<<dim3(40, 32), 256, 0, stream>>>(xseq, wihEn, bih_en, bhh_en, X0en);

  // persistent encoder
  k_enc<<<128, 256, 0, stream>>>(X0en, whhEn, wihEn + WSZ, whhEn + WSZ,
                                 bih_en + 2048, bhh_en + 2048, h0ppE, h1ppE, barE);

  k_fill_xs<<<(32 * 64 * 512 + 255) / 256, 256, 0, stream>>>(h1ppE, emb, target, xs);
  k_gemmX<<<dim3(32, 32), 256, 0, stream>>>(xs, wihDe, bih_de, bhh_de, X0de);

  // persistent decoder
  k_dec<<<200, 256, 0, stream>>>(X0de, whhDe, wihDe + WSZ, whhDe + WSZ,
                                 bih_de + 2048, bhh_de + 2048, h0ppD, h1seq,
                                 awh, att_bh, gempp, xemH, cfH,
                                 att_wv, att_bv, outwH, out_b, ltg, nllb, barD);

  k_loss<<<1, 256, 0, stream>>>(nllb, ltg, out);
}

// Round 3
// 1802.769 us; speedup vs baseline: 2.3512x; 1.7136x over previous
//
#include <hip/hip_runtime.h>

typedef __fp16 f16;
typedef __fp16 f16x4 __attribute__((ext_vector_type(4)));
typedef __fp16 f16x8 __attribute__((ext_vector_type(8)));
typedef float  f32x4 __attribute__((ext_vector_type(4)));

#define DEV static __device__ __forceinline__

DEV f32x4 mfma16(f16x4 a, f16x4 b, f32x4 c) {
  return __builtin_amdgcn_mfma_f32_16x16x16f16(a, b, c, 0, 0, 0);
}
DEV f16x4 lo4(f16x8 v) { return __builtin_shufflevector(v, v, 0, 1, 2, 3); }
DEV f16x4 hi4(f16x8 v) { return __builtin_shufflevector(v, v, 4, 5, 6, 7); }
DEV float sigf(float x) { return 1.f / (1.f + __expf(-x)); }
DEV float tanh_(float x) { float e = __expf(2.f * x); return 1.f - 2.f / (e + 1.f); }

union U8 { float4 f4; float2 f2[2]; };

#define HB 32768   // elements in a [64][512] buffer
#define GB 32768
#define ENC_NB 96
#define DEC_NB 240

// k-permuted staging of 16 f16 into a 72-stride LDS row
DEV void stageRow(const f16* __restrict__ s, f16* __restrict__ dstRow, int ch) {
  U8 u0, u1;
  u0.f4 = *(const float4*)s;
  u1.f4 = *(const float4*)(s + 8);
  *(float2*)(dstRow +  0 + ch * 4) = u0.f2[0];
  *(float2*)(dstRow + 16 + ch * 4) = u0.f2[1];
  *(float2*)(dstRow + 32 + ch * 4) = u1.f2[0];
  *(float2*)(dstRow + 48 + ch * 4) = u1.f2[1];
}

// stage full [64][512] A matrix into sA[8][64][72]
DEV void stageA(const f16* __restrict__ src, f16 (*A)[64][72], int tid) {
  int row = tid >> 2, ch = tid & 3;
  const f16* s = src + (size_t)row * 512 + ch * 16;
  U8 u[8][2];
#pragma unroll
  for (int c = 0; c < 8; ++c) {
    u[c][0].f4 = *(const float4*)(s + c * 64);
    u[c][1].f4 = *(const float4*)(s + c * 64 + 8);
  }
#pragma unroll
  for (int c = 0; c < 8; ++c) {
    f16* d = &A[c][row][0];
    *(float2*)(d +  0 + ch * 4) = u[c][0].f2[0];
    *(float2*)(d + 16 + ch * 4) = u[c][0].f2[1];
    *(float2*)(d + 32 + ch * 4) = u[c][1].f2[0];
    *(float2*)(d + 48 + ch * 4) = u[c][1].f2[1];
  }
}

// 64x32 output tile: wave (mh,ns); acc[2]
DEV void kloop32(const f16 (*Wt)[32][72], const f16 (*A)[64][72],
                 int mh, int ns, int m16, int g4, f32x4 acc[2]) {
#pragma unroll
  for (int c = 0; c < 8; ++c) {
#pragma unroll
    for (int half = 0; half < 2; ++half) {
      f16x8 bf = *(const f16x8*)&Wt[c][ns * 16 + m16][g4 * 16 + half * 8];
      f16x4 bl = lo4(bf), bh = hi4(bf);
#pragma unroll
      for (int mt = 0; mt < 2; ++mt) {
        f16x8 af = *(const f16x8*)&A[c][mh * 32 + mt * 16 + m16][g4 * 16 + half * 8];
        acc[mt] = mfma16(lo4(af), bl, acc[mt]);
        acc[mt] = mfma16(hi4(af), bh, acc[mt]);
      }
    }
  }
}

// 64x64 output tile: wave = n-16-group; acc[4]
DEV void kloop64(const f16* Wg, const f16 (*A)[64][72],
                 int nsG, int m16, int g4, f32x4 acc[4]) {
#pragma unroll
  for (int c = 0; c < 8; ++c) {
#pragma unroll
    for (int half = 0; half < 2; ++half) {
      f16x8 bf = *(const f16x8*)&Wg[((size_t)(c * 64 + nsG * 16 + m16)) * 72 + g4 * 16 + half * 8];
      f16x4 bl = lo4(bf), bh = hi4(bf);
#pragma unroll
      for (int mt = 0; mt < 4; ++mt) {
        f16x8 af = *(const f16x8*)&A[c][mt * 16 + m16][g4 * 16 + half * 8];
        acc[mt] = mfma16(lo4(af), bl, acc[mt]);
        acc[mt] = mfma16(hi4(af), bh, acc[mt]);
      }
    }
  }
}

// device-scope grid barrier: 8 slot counters + flag; nb must be divisible by 8
DEV void gridbar(unsigned* bar, int nb, unsigned target) {
  __syncthreads();
  if (threadIdx.x == 0) {
    int slot = blockIdx.x & 7;
    __hip_atomic_fetch_add(&bar[slot * 16], 1u, __ATOMIC_RELEASE, __HIP_MEMORY_SCOPE_AGENT);
    if (blockIdx.x == 0) {
      unsigned per = (unsigned)(nb >> 3) * target;
      for (int s = 0; s < 8; ++s)
        while (__hip_atomic_load(&bar[s * 16], __ATOMIC_ACQUIRE, __HIP_MEMORY_SCOPE_AGENT) < per)
          __builtin_amdgcn_s_sleep(1);
      __hip_atomic_store(&bar[128], target, __ATOMIC_RELEASE, __HIP_MEMORY_SCOPE_AGENT);
    } else {
      while (__hip_atomic_load(&bar[128], __ATOMIC_RELAXED, __HIP_MEMORY_SCOPE_AGENT) < target)
        __builtin_amdgcn_s_sleep(2);
      (void)__hip_atomic_load(&bar[128], __ATOMIC_ACQUIRE, __HIP_MEMORY_SCOPE_AGENT);
    }
  }
  __syncthreads();
}

// ---------------- prologue kernels ----------------

__global__ void k_convert4(const float* __restrict__ src, f16* __restrict__ dst, int n4) {
  int i = blockIdx.x * 256 + threadIdx.x;
  if (i < n4) {
    float4 v = ((const float4*)src)[i];
    f16x4 o = { (f16)v.x, (f16)v.y, (f16)v.z, (f16)v.w };
    *(f16x4*)(dst + (size_t)i * 4) = o;
  }
}

__global__ void k_wc9(const float* __restrict__ src, f16* __restrict__ dst) {
  int i = blockIdx.x * 256 + threadIdx.x;
  if (i < 512 * 4608) {
    int e = i / 4608, k = i % 4608;
    int rr = k / 512, f = k % 512;
    dst[i] = (f16)src[(size_t)e * 4608 + f * 9 + rr];
  }
}

__global__ void k_cfT(const float* __restrict__ cf, f16* __restrict__ dst) {
  int i = blockIdx.x * 256 + threadIdx.x;
  if (i < 64 * 240 * 512) {
    int b = i / (240 * 512), r = i % (240 * 512);
    int p = r / 512, f = r % 512;
    dst[i] = (f16)cf[((size_t)b * 512 + f) * 240 + p];
  }
}

__global__ void k_maxpool(const float* __restrict__ cf, f16* __restrict__ xseq) {
  int i = blockIdx.x * 256 + threadIdx.x;
  if (i < 40 * 64 * 512) {
    int w = i / (64 * 512), r = i % (64 * 512);
    int b = r / 512, f = r % 512;
    const float* base = cf + ((size_t)b * 512 + f) * 240 + w;
    float m = base[0];
#pragma unroll
    for (int h = 1; h < 6; ++h) m = fmaxf(m, base[h * 40]);
    xseq[i] = (f16)m;
  }
}

__global__ void k_ltarget(const int* __restrict__ target, int* __restrict__ lt) {
  int b = threadIdx.x;
  if (b >= 64) return;
  int row[32];
  row[0] = 0;
  for (int t = 1; t <= 30; ++t) row[t] = target[b * 30 + t - 1];
  row[31] = 0;
  int j = 1;
  while (row[j] != 0) ++j;
  row[j] = 95;
  for (int t = 0; t < 32; ++t) lt[b * 32 + t] = row[t];
}

__global__ void k_fill_xs(const f16* __restrict__ hol, const f16* __restrict__ emb,
                          const int* __restrict__ tgt, f16* __restrict__ xs) {
  int i = blockIdx.x * 256 + threadIdx.x;
  if (i < 32 * 64 * 512) {
    int t = i / (64 * 512), r = i % (64 * 512);
    int b = r / 512, u = r % 512;
    f16 v;
    if (t == 0) v = hol[b * 512 + u];
    else {
      int tok = (t == 1) ? 95 : tgt[b * 30 + t - 2];
      v = emb[(size_t)tok * 512 + u];
    }
    xs[i] = v;
  }
}

// ---------------- batched X0 GEMM ----------------
__global__ __launch_bounds__(256) void k_gemmX(
    const f16* __restrict__ A, const f16* __restrict__ W,
    const float* __restrict__ b1, const float* __restrict__ b2,
    f16* __restrict__ C)
{
  __shared__ f16 At[64][72];
  __shared__ f16 Bt[64][72];
  const int t = threadIdx.x, lane = t & 63, g = t >> 6;
  f32x4 acc[4] = {};
  const int m16 = lane & 15, g4 = lane >> 4;
  const size_t arow0 = (size_t)blockIdx.x * 64;

  for (int k0 = 0; k0 < 512; k0 += 64) {
    __syncthreads();
    { int row = t >> 2, ch = t & 3;
      stageRow(A + (arow0 + row) * 512 + k0 + ch * 16, &At[row][0], ch); }
    { int row = t >> 2, ch = t & 3;
      stageRow(W + ((size_t)blockIdx.y * 64 + row) * 512 + k0 + ch * 16, &Bt[row][0], ch); }
    __syncthreads();
#pragma unroll
    for (int half = 0; half < 2; ++half) {
      f16x8 bf = *(const f16x8*)&Bt[g * 16 + m16][g4 * 16 + half * 8];
      f16x4 bl = lo4(bf), bh = hi4(bf);
#pragma unroll
      for (int mt = 0; mt < 4; ++mt) {
        f16x8 af = *(const f16x8*)&At[mt * 16 + m16][g4 * 16 + half * 8];
        acc[mt] = mfma16(lo4(af), bl, acc[mt]);
        acc[mt] = mfma16(hi4(af), bh, acc[mt]);
      }
    }
  }
  int e = blockIdx.y * 64 + g * 16 + m16;
  float bias = b1[e] + b2[e];
#pragma unroll
  for (int mt = 0; mt < 4; ++mt)
#pragma unroll
    for (int r = 0; r < 4; ++r)
      C[(arow0 + mt * 16 + g4 * 4 + r) * 2048 + e] = (f16)(acc[mt][r] + bias);
}

// ---------------- conv 3x3 as 9 shifted MFMA GEMMs (f16 out) ----------------
__global__ __launch_bounds__(256, 1) void k_conv(
    const f16* __restrict__ cfT, const f16* __restrict__ wc9,
    const float* __restrict__ cb, f16* __restrict__ xemH)
{
  __shared__ f16 At[240][40];
  __shared__ f16 Bt[128][40];
  const int t = threadIdx.x, lane = t & 63, w = t >> 6;
  const int b = blockIdx.y, eb = blockIdx.x * 128;
  const int m16 = lane & 15, g4 = lane >> 4;
  f32x4 acc[15][2] = {};

  for (int kr = 0; kr < 9; ++kr) {
    int dh = kr / 3 - 1, dw = kr % 3 - 1;
    for (int f0 = 0; f0 < 512; f0 += 32) {
      __syncthreads();
      if (t < 240) {
        int hh = t / 40 + dh, ww = t % 40 + dw;
        if (hh >= 0 && hh < 6 && ww >= 0 && ww < 40) {
          const f16* s = cfT + ((size_t)(b * 240 + hh * 40 + ww) * 512 + f0);
          U8 u0, u1, u2, u3;
          u0.f4 = *(const float4*)s;        u1.f4 = *(const float4*)(s + 8);
          u2.f4 = *(const float4*)(s + 16); u3.f4 = *(const float4*)(s + 24);
          *(float2*)&At[t][ 0] = u0.f2[0];
          *(float2*)&At[t][ 8] = u0.f2[1];
          *(float2*)&At[t][16] = u1.f2[0];
          *(float2*)&At[t][24] = u1.f2[1];
          *(float2*)&At[t][ 4] = u2.f2[0];
          *(float2*)&At[t][12] = u2.f2[1];
          *(float2*)&At[t][20] = u3.f2[0];
          *(float2*)&At[t][28] = u3.f2[1];
        } else {
          float2 z = make_float2(0.f, 0.f);
          *(float2*)&At[t][ 0] = z; *(float2*)&At[t][ 8] = z;
          *(float2*)&At[t][16] = z; *(float2*)&At[t][24] = z;
          *(float2*)&At[t][ 4] = z; *(float2*)&At[t][12] = z;
          *(float2*)&At[t][20] = z; *(float2*)&At[t][28] = z;
        }
      }
      {
        int n = t >> 1, ch = t & 1;
        const f16* s = wc9 + (size_t)(eb + n) * 4608 + kr * 512 + f0 + ch * 16;
        U8 u0, u1;
        u0.f4 = *(const float4*)s; u1.f4 = *(const float4*)(s + 8);
        *(float2*)&Bt[n][ 0 + ch * 4] = u0.f2[0];
        *(float2*)&Bt[n][ 8 + ch * 4] = u0.f2[1];
        *(float2*)&Bt[n][16 + ch * 4] = u1.f2[0];
        *(float2*)&Bt[n][24 + ch * 4] = u1.f2[1];
      }
      __syncthreads();
      f16x8 b0 = *(const f16x8*)&Bt[w * 32 + m16][g4 * 8];
      f16x8 b1v = *(const f16x8*)&Bt[w * 32 + 16 + m16][g4 * 8];
      f16x4 b0l = lo4(b0), b0h = hi4(b0), b1l = lo4(b1v), b1h = hi4(b1v);
#pragma unroll
      for (int mt = 0; mt < 15; ++mt) {
        f16x8 af = *(const f16x8*)&At[mt * 16 + m16][g4 * 8];
        f16x4 al = lo4(af), ah = hi4(af);
        acc[mt][0] = mfma16(al, b0l, acc[mt][0]);
        acc[mt][1] = mfma16(al, b1l, acc[mt][1]);
        acc[mt][0] = mfma16(ah, b0h, acc[mt][0]);
        acc[mt][1] = mfma16(ah, b1h, acc[mt][1]);
      }
    }
  }
#pragma unroll
  for (int nt = 0; nt < 2; ++nt) {
    int e = eb + w * 32 + nt * 16 + m16;
    float bias = cb[e];
#pragma unroll
    for (int mt = 0; mt < 15; ++mt)
#pragma unroll
      for (int r = 0; r < 4; ++r) {
        int p = mt * 16 + g4 * 4 + r;
        xemH[((size_t)(b * 240 + p)) * 512 + e] = (f16)(acc[mt][nt][r] + bias);
      }
  }
}

// ---------------- persistent encoder: L0e 32 blocks (16u), L1e 64 blocks (8u) ----------------
__global__ __launch_bounds__(256, 1) void k_enc2(
    const f16* __restrict__ G0, const f16* __restrict__ whh0,
    const f16* __restrict__ wih1, const f16* __restrict__ whh1,
    const float* __restrict__ bih1, const float* __restrict__ bhh1,
    f16* __restrict__ h0pp, f16* __restrict__ h1pp,
    unsigned* __restrict__ bar)
{
  __shared__ __align__(16) char smem[147456];
  const int tid = threadIdx.x, lane = tid & 63, w = tid >> 6;
  const int m16 = lane & 15, g4 = lane >> 4;
  const int bid = blockIdx.x;

  if (bid < 32) {   // layer-0, 16 u-cols
    f16 (*sW)[64][72] = (f16(*)[64][72])smem;
    f16 (*sA)[64][72] = (f16(*)[64][72])(smem + 73728);
    float* sG = (float*)(smem + 73728);   // [4][64][17]
    const int utile = bid;
    { int r = tid >> 2, ch = tid & 3;
      int grow = (r >> 4) * 512 + utile * 16 + (r & 15);
      for (int c = 0; c < 8; ++c)
        stageRow(whh0 + (size_t)grow * 512 + c * 64 + ch * 16, &sW[c][r][0], ch);
    }
    float cst[4] = {0.f, 0.f, 0.f, 0.f};
    for (int s = 0; s <= 40; ++s) {
      if (s < 40) {
        int t = s;
        f32x4 acc[4] = {};
        stageA(h0pp + (size_t)(s & 1) * HB, sA, tid);
        __syncthreads();
        kloop64((const f16*)sW, sA, w, m16, g4, acc);
        __syncthreads();
#pragma unroll
        for (int mt = 0; mt < 4; ++mt)
#pragma unroll
          for (int r = 0; r < 4; ++r)
            sG[((size_t)w * 64 + mt * 16 + g4 * 4 + r) * 17 + m16] = acc[mt][r];
        __syncthreads();
        f16* hout = h0pp + (size_t)((s + 1) & 1) * HB;
#pragma unroll
        for (int oi = 0; oi < 4; ++oi) {
          int idx = tid + oi * 256;
          int b = idx >> 4, u = idx & 15;
          const f16* gp = G0 + ((size_t)(t * 64 + b)) * 2048 + utile * 16 + u;
          float gi = sG[(0 * 64 + b) * 17 + u] + (float)gp[0];
          float gf = sG[(1 * 64 + b) * 17 + u] + (float)gp[512];
          float gg = sG[(2 * 64 + b) * 17 + u] + (float)gp[1024];
          float go = sG[(3 * 64 + b) * 17 + u] + (float)gp[1536];
          float cn = sigf(gf) * cst[oi] + sigf(gi) * tanh_(gg);
          float hn = sigf(go) * tanh_(cn);
          cst[oi] = cn;
          hout[b * 512 + utile * 16 + u] = (f16)hn;
        }
      }
      gridbar(bar, ENC_NB, (unsigned)(s + 1));
    }
  } else {          // layer-1, 8 u-cols
    f16 (*sW2)[8][32][72] = (f16(*)[8][32][72])smem;
    f16 (*sA)[64][72] = (f16(*)[64][72])(smem + 73728);
    float* sG = (float*)(smem + 73728);   // [4][64][9]
    const int utile = bid - 32;
    const int mh = w >> 1, ns = w & 1;
    { int mat = tid >> 7;
      int r = (tid >> 2) & 31, ch = tid & 3;
      int grow = (r >> 3) * 512 + utile * 8 + (r & 7);
      const f16* Wsrc = (mat == 0) ? wih1 : whh1;
      for (int c = 0; c < 8; ++c)
        stageRow(Wsrc + (size_t)grow * 512 + c * 64 + ch * 16, &sW2[mat][c][r][0], ch);
    }
    float badd[4];
    { int ul = tid & 7;
#pragma unroll
      for (int g = 0; g < 4; ++g) {
        int rr = g * 512 + utile * 8 + ul;
        badd[g] = bih1[rr] + bhh1[rr];
      }
    }
    float cst[2] = {0.f, 0.f};
    for (int s = 0; s <= 40; ++s) {
      if (s >= 1) {
        f32x4 acc[2] = {};
        stageA(h0pp + (size_t)(s & 1) * HB, sA, tid);   // h0[t]
        __syncthreads();
        kloop32(sW2[0], sA, mh, ns, m16, g4, acc);
        __syncthreads();
        stageA(h1pp + (size_t)(s & 1) * HB, sA, tid);   // h1[t-1]
        __syncthreads();
        kloop32(sW2[1], sA, mh, ns, m16, g4, acc);
        __syncthreads();
        { int nl = ns * 16 + m16;
#pragma unroll
          for (int mt = 0; mt < 2; ++mt)
#pragma unroll
            for (int r = 0; r < 4; ++r) {
              int b = mh * 32 + mt * 16 + g4 * 4 + r;
              sG[((nl >> 3) * 64 + b) * 9 + (nl & 7)] = acc[mt][r];
            }
        }
        __syncthreads();
        f16* hout = h1pp + (size_t)((s - 1) & 1) * HB;
#pragma unroll
        for (int oi = 0; oi < 2; ++oi) {
          int idx = tid + oi * 256;
          int b = idx >> 3, ul = idx & 7;
          float gi = sG[(0 * 64 + b) * 9 + ul] + badd[0];
          float gf = sG[(1 * 64 + b) * 9 + ul] + badd[1];
          float gg = sG[(2 * 64 + b) * 9 + ul] + badd[2];
          float go = sG[(3 * 64 + b) * 9 + ul] + badd[3];
          float cn = sigf(gf) * cst[oi] + sigf(gi) * tanh_(gg);
          float hn = sigf(go) * tanh_(cn);
          cst[oi] = cn;
          hout[b * 512 + utile * 8 + ul] = (f16)hn;
        }
      }
      gridbar(bar, ENC_NB, (unsigned)(s + 1));
    }
  }
}

// ---------------- persistent decoder ----------------
// blocks: [0,32) L0 | [32,96) L1 | [96,104) GEM | [104,232) ATT | [232,238) LOG | 238 NLL | 239 dummy
__global__ __launch_bounds__(256, 1) void k_dec2(
    const f16* __restrict__ G0, const f16* __restrict__ whh0,
    const f16* __restrict__ wih1, const f16* __restrict__ whh1,
    const float* __restrict__ bih1, const float* __restrict__ bhh1,
    f16* __restrict__ h0pp, f16* __restrict__ h1seq,
    const f16* __restrict__ awh, const float* __restrict__ gbias,
    float* __restrict__ gempp,
    const f16* __restrict__ xemH, const f16* __restrict__ cfT,
    const float* __restrict__ wv, const float* __restrict__ bv,
    const f16* __restrict__ outwH, const float* __restrict__ outb,
    const int* __restrict__ ltg, float* __restrict__ nllb,
    float* __restrict__ escb, f16* __restrict__ attH, float* __restrict__ lgt,
    unsigned* __restrict__ bar)
{
  __shared__ __align__(16) char smem[147456];
  const int tid = threadIdx.x, lane = tid & 63, w = tid >> 6;
  const int m16 = lane & 15, g4 = lane >> 4;
  const int bid = blockIdx.x;

  if (bid < 32) {  // ---- L0 ----
    f16 (*sW)[64][72] = (f16(*)[64][72])smem;
    f16 (*sA)[64][72] = (f16(*)[64][72])(smem + 73728);
    float* sG = (float*)(smem + 73728);
    const int utile = bid;
    { int r = tid >> 2, ch = tid & 3;
      int grow = (r >> 4) * 512 + utile * 16 + (r & 15);
      for (int c = 0; c < 8; ++c)
        stageRow(whh0 + (size_t)grow * 512 + c * 64 + ch * 16, &sW[c][r][0], ch);
    }
    float cst[4] = {0.f, 0.f, 0.f, 0.f};
    for (int s = 0; s <= 37; ++s) {
      if (s < 32) {
        int t = s;
        f32x4 acc[4] = {};
        stageA(h0pp + (size_t)(s & 1) * HB, sA, tid);
        __syncthreads();
        kloop64((const f16*)sW, sA, w, m16, g4, acc);
        __syncthreads();
#pragma unroll
        for (int mt = 0; mt < 4; ++mt)
#pragma unroll
          for (int r = 0; r < 4; ++r)
            sG[((size_t)w * 64 + mt * 16 + g4 * 4 + r) * 17 + m16] = acc[mt][r];
        __syncthreads();
        f16* hout = h0pp + (size_t)((s + 1) & 1) * HB;
#pragma unroll
        for (int oi = 0; oi < 4; ++oi) {
          int idx = tid + oi * 256;
          int b = idx >> 4, u = idx & 15;
          const f16* gp = G0 + ((size_t)(t * 64 + b)) * 2048 + utile * 16 + u;
          float gi = sG[(0 * 64 + b) * 17 + u] + (float)gp[0];
          float gf = sG[(1 * 64 + b) * 17 + u] + (float)gp[512];
          float gg = sG[(2 * 64 + b) * 17 + u] + (float)gp[1024];
          float go = sG[(3 * 64 + b) * 17 + u] + (float)gp[1536];
          float cn = sigf(gf) * cst[oi] + sigf(gi) * tanh_(gg);
          float hn = sigf(go) * tanh_(cn);
          cst[oi] = cn;
          hout[b * 512 + utile * 16 + u] = (f16)hn;
        }
      }
      gridbar(bar, DEC_NB, (unsigned)(s + 1));
    }
  } else if (bid < 96) {  // ---- L1 ----
    f16 (*sW2)[8][32][72] = (f16(*)[8][32][72])smem;
    f16 (*sA)[64][72] = (f16(*)[64][72])(smem + 73728);
    float* sG = (float*)(smem + 73728);
    const int utile = bid - 32;
    const int mh = w >> 1, ns = w & 1;
    { int mat = tid >> 7;
      int r = (tid >> 2) & 31, ch = tid & 3;
      int grow = (r >> 3) * 512 + utile * 8 + (r & 7);
      const f16* Wsrc = (mat == 0) ? wih1 : whh1;
      for (int c = 0; c < 8; ++c)
        stageRow(Wsrc + (size_t)grow * 512 + c * 64 + ch * 16, &sW2[mat][c][r][0], ch);
    }
    float badd[4];
    { int ul = tid & 7;
#pragma unroll
      for (int g = 0; g < 4; ++g) {
        int rr = g * 512 + utile * 8 + ul;
        badd[g] = bih1[rr] + bhh1[rr];
      }
    }
    float cst[2] = {0.f, 0.f};
    for (int s = 0; s <= 37; ++s) {
      if (s >= 1 && s <= 32) {
        f32x4 acc[2] = {};
        stageA(h0pp + (size_t)(s & 1) * HB, sA, tid);          // h0[t]
        __syncthreads();
        kloop32(sW2[0], sA, mh, ns, m16, g4, acc);
        __syncthreads();
        stageA(h1seq + (size_t)(s - 1) * HB, sA, tid);         // h1[t-1]
        __syncthreads();
        kloop32(sW2[1], sA, mh, ns, m16, g4, acc);
        __syncthreads();
        { int nl = ns * 16 + m16;
#pragma unroll
          for (int mt = 0; mt < 2; ++mt)
#pragma unroll
            for (int r = 0; r < 4; ++r) {
              int b = mh * 32 + mt * 16 + g4 * 4 + r;
              sG[((nl >> 3) * 64 + b) * 9 + (nl & 7)] = acc[mt][r];
            }
        }
        __syncthreads();
        f16* hout = h1seq + (size_t)s * HB;
#pragma unroll
        for (int oi = 0; oi < 2; ++oi) {
          int idx = tid + oi * 256;
          int b = idx >> 3, ul = idx & 7;
          float gi = sG[(0 * 64 + b) * 9 + ul] + badd[0];
          float gf = sG[(1 * 64 + b) * 9 + ul] + badd[1];
          float gg = sG[(2 * 64 + b) * 9 + ul] + badd[2];
          float go = sG[(3 * 64 + b) * 9 + ul] + badd[3];
          float cn = sigf(gf) * cst[oi] + sigf(gi) * tanh_(gg);
          float hn = sigf(go) * tanh_(cn);
          cst[oi] = cn;
          hout[b * 512 + utile * 8 + ul] = (f16)hn;
        }
      }
      gridbar(bar, DEC_NB, (unsigned)(s + 1));
    }
  } else if (bid < 104) {  // ---- GEM ----
    f16* sWg = (f16*)smem;                       // [8][64][72]
    f16 (*sA)[64][72] = (f16(*)[64][72])(smem + 73728);
    const int gtile = bid - 96;
    { int r = tid >> 2, ch = tid & 3;
      for (int c = 0; c < 8; ++c)
        stageRow(awh + (size_t)(gtile * 64 + r) * 512 + c * 64 + ch * 16,
                 sWg + ((size_t)(c * 64 + r)) * 72, ch);
    }
    float gbias_r = gbias[gtile * 64 + w * 16 + m16];
    for (int s = 0; s <= 37; ++s) {
      if (s >= 2 && s <= 33) {
        int t = s - 2;
        f32x4 acc[4] = {};
        stageA(h1seq + (size_t)(s - 1) * HB, sA, tid);   // h1[t]
        __syncthreads();
        kloop64(sWg, sA, w, m16, g4, acc);
        __syncthreads();
        float* gout = gempp + (size_t)(t & 1) * GB;
        int e = gtile * 64 + w * 16 + m16;
#pragma unroll
        for (int mt = 0; mt < 4; ++mt)
#pragma unroll
          for (int r = 0; r < 4; ++r)
            gout[(mt * 16 + g4 * 4 + r) * 512 + e] = acc[mt][r] + gbias_r;
      }
      gridbar(bar, DEC_NB, (unsigned)(s + 1));
    }
  } else if (bid < 232) {  // ---- ATT: 2 blocks per batch ----
    f16* sXem = (f16*)smem;                      // [120][512]
    float* aE   = (float*)(smem + 122880);       // [240] scores scratch (unused now)
    float* aAl  = (float*)(smem + 123840);       // [240] alpha
    float* aRed = (float*)(smem + 124800);       // [256]
    const int aid = bid - 104, ab = aid >> 1, hf = aid & 1;
    (void)aE;
    // resident xem half
    for (int i = tid; i < 120 * 64; i += 256) {
      int row = i >> 6, seg = i & 63;
      *(f16x8*)&sXem[row * 512 + seg * 8] =
          *(const f16x8*)(xemH + ((size_t)(ab * 240 + hf * 120 + row)) * 512 + seg * 8);
    }
    float w8[8];
    { const float4* wp = (const float4*)(wv + lane * 8);
      float4 wa = wp[0], wb = wp[1];
      w8[0] = wa.x; w8[1] = wa.y; w8[2] = wa.z; w8[3] = wa.w;
      w8[4] = wb.x; w8[5] = wb.y; w8[6] = wb.z; w8[7] = wb.w;
    }
    float bv0 = bv[0];
    __syncthreads();
    for (int s = 0; s <= 37; ++s) {
      if (s >= 3 && s <= 34) {     // SCORE for t
        int t = s - 3;
        float g8[8];
        const float4* gp = (const float4*)(gempp + (size_t)(t & 1) * GB + ab * 512 + lane * 8);
        float4 ga = gp[0], gb4 = gp[1];
        g8[0] = ga.x; g8[1] = ga.y; g8[2] = ga.z; g8[3] = ga.w;
        g8[4] = gb4.x; g8[5] = gb4.y; g8[6] = gb4.z; g8[7] = gb4.w;
        for (int r = w; r < 120; r += 4) {
          f16x8 xv = *(const f16x8*)&sXem[r * 512 + lane * 8];
          float ssum = 0.f;
#pragma unroll
          for (int j = 0; j < 8; ++j)
            ssum += tanh_((float)xv[j] + g8[j]) * w8[j];
#pragma unroll
          for (int m = 32; m; m >>= 1) ssum += __shfl_xor(ssum, m);
          if (lane == 0)
            escb[(size_t)(t & 1) * 15360 + ab * 240 + hf * 120 + r] = ssum + bv0;
        }
      }
      if (s >= 4 && s <= 35) {     // SOFTMAX + CTX for t2
        int t2 = s - 4;
        const float* er = escb + (size_t)(t2 & 1) * 15360 + ab * 240;
        float v = (tid < 240) ? er[tid] : -1e30f;
        aRed[tid] = v; __syncthreads();
        for (int st = 128; st; st >>= 1) { if (tid < st) aRed[tid] = fmaxf(aRed[tid], aRed[tid + st]); __syncthreads(); }
        float mx = aRed[0]; __syncthreads();
        float ex = (tid < 240) ? __expf(v - mx) : 0.f;
        aRed[tid] = ex; __syncthreads();
        for (int st = 128; st; st >>= 1) { if (tid < st) aRed[tid] += aRed[tid + st]; __syncthreads(); }
        float inv = 1.f / aRed[0];
        __syncthreads();
        if (tid < 240) aAl[tid] = ex * inv;
        __syncthreads();
        int f = hf * 256 + tid;
        const f16* cp = cfT + (size_t)(ab * 240) * 512 + f;
        float a = 0.f;
#pragma unroll 8
        for (int p = 0; p < 240; ++p) a += aAl[p] * (float)cp[(size_t)p * 512];
        attH[(size_t)(t2 & 1) * HB + ab * 512 + f] = (f16)a;
      }
      gridbar(bar, DEC_NB, (unsigned)(s + 1));
    }
  } else if (bid < 238) {  // ---- LOG: 6 blocks x 16 output rows ----
    f16 (*sWl)[16][72] = (f16(*)[16][72])smem;   // [16][16][72]
    f16 (*sA)[64][72] = (f16(*)[64][72])(smem + 73728);
    const int blk = bid - 232;
    if (tid < 64) {
      int r = tid >> 2, ch = tid & 3;
      for (int c = 0; c < 16; ++c)
        stageRow(outwH + (size_t)(blk * 16 + r) * 1024 + c * 64 + ch * 16, &sWl[c][r][0], ch);
    }
    float ob_r = outb[blk * 16 + m16];
    for (int s = 0; s <= 37; ++s) {
      if (s >= 5 && s <= 36) {
        int t3 = s - 5;
        f32x4 acc = {};
        stageA(h1seq + (size_t)(t3 + 1) * HB, sA, tid);
        __syncthreads();
#pragma unroll
        for (int c = 0; c < 8; ++c)
#pragma unroll
          for (int h2 = 0; h2 < 2; ++h2) {
            f16x8 bf = *(const f16x8*)&sWl[c][m16][g4 * 16 + h2 * 8];
            f16x8 af = *(const f16x8*)&sA[c][w * 16 + m16][g4 * 16 + h2 * 8];
            acc = mfma16(lo4(af), lo4(bf), acc);
            acc = mfma16(hi4(af), hi4(bf), acc);
          }
        __syncthreads();
        stageA(attH + (size_t)(t3 & 1) * HB, sA, tid);
        __syncthreads();
#pragma unroll
        for (int c = 0; c < 8; ++c)
#pragma unroll
          for (int h2 = 0; h2 < 2; ++h2) {
            f16x8 bf = *(const f16x8*)&sWl[8 + c][m16][g4 * 16 + h2 * 8];
            f16x8 af = *(const f16x8*)&sA[c][w * 16 + m16][g4 * 16 + h2 * 8];
            acc = mfma16(lo4(af), lo4(bf), acc);
            acc = mfma16(hi4(af), hi4(bf), acc);
          }
        __syncthreads();
#pragma unroll
        for (int r = 0; r < 4; ++r) {
          int b = w * 16 + g4 * 4 + r;
          lgt[(size_t)(t3 & 1) * 6144 + b * 96 + blk * 16 + m16] = acc[r] + ob_r;
        }
      }
      gridbar(bar, DEC_NB, (unsigned)(s + 1));
    }
  } else if (bid == 238) {  // ---- NLL ----
    float* sL = (float*)smem;   // [64][97]
    for (int s = 0; s <= 37; ++s) {
      if (s >= 6) {
        int t4 = s - 6;
        for (int i = tid; i < 6144; i += 256) {
          int b = i / 96, j = i - b * 96;
          sL[b * 97 + j] = lgt[(size_t)(t4 & 1) * 6144 + i];
        }
        __syncthreads();
        if (tid < 64) {
          int b = tid;
          float mx = -1e30f;
          for (int j = 0; j < 96; ++j) mx = fmaxf(mx, sL[b * 97 + j]);
          float sum = 0.f;
          for (int j = 0; j < 96; ++j) sum += __expf(sL[b * 97 + j] - mx);
          float lse = mx + __logf(sum);
          int tok = ltg[b * 32 + t4];
          nllb[t4 * 64 + b] = (tok != 0) ? (lse - sL[b * 97 + tok]) : 0.f;
        }
        __syncthreads();
      }
      gridbar(bar, DEC_NB, (unsigned)(s + 1));
    }
  } else {  // dummy
    for (int s = 0; s <= 37; ++s) gridbar(bar, DEC_NB, (unsigned)(s + 1));
  }
}

__global__ void k_loss(const float* __restrict__ nll, const int* __restrict__ ltg,
                       float* __restrict__ out) {
  __shared__ float sa[256], sb[256];
  int t = threadIdx.x;
  float a = 0.f, m = 0.f;
  for (int i = t; i < 2048; i += 256) {
    a += nll[i];
    m += (ltg[i] != 0) ? 1.f : 0.f;
  }
  sa[t] = a; sb[t] = m; __syncthreads();
  for (int s = 128; s; s >>= 1) { if (t < s) { sa[t] += sa[t + s]; sb[t] += sb[t + s]; } __syncthreads(); }
  if (t == 0) out[0] = sa[0] / sb[0];
}

// ---------------- host ----------------

extern "C" void kernel_launch(void* const* d_in, const int* in_sizes, int n_in,
                              void* d_out, int out_size, void* d_ws, size_t ws_size,
                              hipStream_t stream) {
  (void)in_sizes; (void)n_in; (void)out_size; (void)ws_size;
  const float* conv_f = (const float*)d_in[0];
  const int*   target = (const int*)d_in[1];
  const float* wih_en = (const float*)d_in[2];
  const float* whh_en = (const float*)d_in[3];
  const float* bih_en = (const float*)d_in[4];
  const float* bhh_en = (const float*)d_in[5];
  const float* embed  = (const float*)d_in[6];
  const float* wih_de = (const float*)d_in[7];
  const float* whh_de = (const float*)d_in[8];
  const float* bih_de = (const float*)d_in[9];
  const float* bhh_de = (const float*)d_in[10];
  const float* att_wh = (const float*)d_in[11];
  const float* att_bh = (const float*)d_in[12];
  const float* att_cw = (const float*)d_in[13];
  const float* att_cb = (const float*)d_in[14];
  const float* att_wv = (const float*)d_in[15];
  const float* att_bv = (const float*)d_in[16];
  const float* out_w  = (const float*)d_in[17];
  const float* out_b  = (const float*)d_in[18];
  float* out = (float*)d_out;

  size_t o = 0;
  char* base = (char*)d_ws;
  auto take = [&](size_t bytes) -> void* {
    void* p = base + o;
    o += (bytes + 255) & ~(size_t)255;
    return p;
  };
  const size_t WSZ = (size_t)2048 * 512;
  f16* wihEn = (f16*)take(2 * WSZ * 2);
  f16* whhEn = (f16*)take(2 * WSZ * 2);
  f16* wihDe = (f16*)take(2 * WSZ * 2);
  f16* whhDe = (f16*)take(2 * WSZ * 2);
  f16* awh   = (f16*)take((size_t)512 * 512 * 2);
  f16* emb   = (f16*)take((size_t)96 * 512 * 2);
  f16* wc9   = (f16*)take((size_t)512 * 4608 * 2);
  f16* cfT   = (f16*)take((size_t)64 * 240 * 512 * 2);
  f16* xseq  = (f16*)take((size_t)40 * 64 * 512 * 2);
  f16* xs    = (f16*)take((size_t)32 * 64 * 512 * 2);
  f16* xemH  = (f16*)take((size_t)64 * 240 * 512 * 2);
  f16* outwH = (f16*)take((size_t)96 * 1024 * 2);
  f16* X0en  = (f16*)take((size_t)2560 * 2048 * 2);
  f16* X0de  = (f16*)take((size_t)2048 * 2048 * 2);
  f16* hstate = (f16*)take((size_t)6 * HB * 2);
  f16* h0ppE = hstate;
  f16* h1ppE = hstate + 2 * HB;
  f16* h0ppD = hstate + 4 * HB;
  f16* h1seq = (f16*)take((size_t)33 * HB * 2);
  float* gempp = (float*)take((size_t)2 * GB * 4);
  float* escb  = (float*)take((size_t)2 * 64 * 240 * 4);
  f16*   attH  = (f16*)take((size_t)2 * HB * 2);
  float* lgt   = (float*)take((size_t)2 * 64 * 96 * 4);
  float* nllb  = (float*)take((size_t)2048 * 4);
  int*   ltg   = (int*)take((size_t)2048 * 4);
  unsigned* barE = (unsigned*)take(1024);
  unsigned* barD = (unsigned*)take(1024);

  // prologue conversions
  k_convert4<<<2048, 256, 0, stream>>>(wih_en, wihEn, (int)(2 * WSZ / 4));
  k_convert4<<<2048, 256, 0, stream>>>(whh_en, whhEn, (int)(2 * WSZ / 4));
  k_convert4<<<2048, 256, 0, stream>>>(wih_de, wihDe, (int)(2 * WSZ / 4));
  k_convert4<<<2048, 256, 0, stream>>>(whh_de, whhDe, (int)(2 * WSZ / 4));
  k_convert4<<<256, 256, 0, stream>>>(att_wh, awh, 512 * 512 / 4);
  k_convert4<<<48, 256, 0, stream>>>(embed, emb, 96 * 512 / 4);
  k_convert4<<<96, 256, 0, stream>>>(out_w, outwH, 96 * 1024 / 4);
  k_wc9<<<(512 * 4608 + 255) / 256, 256, 0, stream>>>(att_cw, wc9);
  k_cfT<<<(64 * 240 * 512 + 255) / 256, 256, 0, stream>>>(conv_f, cfT);
  k_maxpool<<<(40 * 64 * 512 + 255) / 256, 256, 0, stream>>>(conv_f, xseq);
  k_ltarget<<<1, 64, 0, stream>>>(target, ltg);
  hipMemsetAsync(hstate, 0, (size_t)6 * HB * 2, stream);
  hipMemsetAsync(h1seq, 0, (size_t)HB * 2, stream);
  hipMemsetAsync(barE, 0, 2048, stream);   // barE+barD contiguous

  k_conv<<<dim3(4, 64), 256, 0, stream>>>(cfT, wc9, att_cb, xemH);
  k_gemmX<<<dim3(40, 32), 256, 0, stream>>>(xseq, wihEn, bih_en, bhh_en, X0en);

  k_enc2<<<ENC_NB, 256, 0, stream>>>(X0en, whhEn, wihEn + WSZ, whhEn + WSZ,
                                     bih_en + 2048, bhh_en + 2048, h0ppE, h1ppE, barE);

  k_fill_xs<<<(32 * 64 * 512 + 255) / 256, 256, 0, stream>>>(h1ppE + HB, emb, target, xs);
  k_gemmX<<<dim3(32, 32), 256, 0, stream>>>(xs, wihDe, bih_de, bhh_de, X0de);

  k_dec2<<<DEC_NB, 256, 0, stream>>>(X0de, whhDe, wihDe + WSZ, whhDe + WSZ,
                                     bih_de + 2048, bhh_de + 2048, h0ppD, h1seq,
                                     awh, att_bh, gempp, xemH, cfT,
                                     att_wv, att_bv, outwH, out_b, ltg, nllb,
                                     escb, attH, lgt, barD);

  k_loss<<<1, 256, 0, stream>>>(nllb, ltg, out);
}

// Round 4
// 1234.100 us; speedup vs baseline: 3.4346x; 1.4608x over previous
//
#include <hip/hip_runtime.h>

typedef __fp16 f16;
typedef __fp16 f16x4 __attribute__((ext_vector_type(4)));
typedef __fp16 f16x8 __attribute__((ext_vector_type(8)));
typedef float  f32x4 __attribute__((ext_vector_type(4)));
typedef unsigned long long ull;

#define DEV static __device__ __forceinline__

DEV f32x4 mfma16(f16x4 a, f16x4 b, f32x4 c) {
  return __builtin_amdgcn_mfma_f32_16x16x16f16(a, b, c, 0, 0, 0);
}
DEV f16x4 lo4(f16x8 v) { return __builtin_shufflevector(v, v, 0, 1, 2, 3); }
DEV f16x4 hi4(f16x8 v) { return __builtin_shufflevector(v, v, 4, 5, 6, 7); }
DEV float sigf(float x) { return 1.f / (1.f + __expf(-x)); }
DEV float tanh_(float x) { float e = __expf(2.f * x); return 1.f - 2.f / (e + 1.f); }

union U8 { float4 f4; float2 f2[2]; };
union H2 { unsigned u; f16 h[2]; };

#define HB 32768   // f16 elements in a [64][512] buffer

// ---- uncached (agent-coherent, L3-direct) access helpers ----
DEV ull ldU(const ull* p) {
  return __hip_atomic_load(p, __ATOMIC_RELAXED, __HIP_MEMORY_SCOPE_AGENT);
}
DEV void stU32(unsigned* p, unsigned v) {
  __hip_atomic_store(p, v, __ATOMIC_RELAXED, __HIP_MEMORY_SCOPE_AGENT);
}

// poll two 8-slot counter lines (threads 0-7 line A, 8-15 line B)
DEV void waitTwo(const unsigned* lineA, unsigned tgtA,
                 const unsigned* lineB, unsigned tgtB) {
  const int tid = threadIdx.x;
  if (tid < 8) {
    while (__hip_atomic_load(lineA + tid * 16, __ATOMIC_RELAXED, __HIP_MEMORY_SCOPE_AGENT) < tgtA)
      __builtin_amdgcn_s_sleep(1);
  } else if (tid < 16) {
    while (__hip_atomic_load(lineB + (tid - 8) * 16, __ATOMIC_RELAXED, __HIP_MEMORY_SCOPE_AGENT) < tgtB)
      __builtin_amdgcn_s_sleep(1);
  }
  __syncthreads();
  asm volatile("" ::: "memory");
}

DEV void signalDone(unsigned* line, int slot) {
  asm volatile("s_waitcnt vmcnt(0)" ::: "memory");  // per-wave drain of h stores
  __syncthreads();
  if (threadIdx.x == 0)
    __hip_atomic_fetch_add(line + slot * 16, 1u, __ATOMIC_RELAXED, __HIP_MEMORY_SCOPE_AGENT);
}

// k-permuted staging of 16 f16 (cached path, for weights / batched GEMMs)
DEV void stageRow(const f16* __restrict__ s, f16* __restrict__ dstRow, int ch) {
  U8 u0, u1;
  u0.f4 = *(const float4*)s;
  u1.f4 = *(const float4*)(s + 8);
  *(float2*)(dstRow +  0 + ch * 4) = u0.f2[0];
  *(float2*)(dstRow + 16 + ch * 4) = u0.f2[1];
  *(float2*)(dstRow + 32 + ch * 4) = u1.f2[0];
  *(float2*)(dstRow + 48 + ch * 4) = u1.f2[1];
}

// stage [64][512] f16 A-matrix from global via coherent 8B loads into sA[8][64][72]
DEV void stageAu(const ull* __restrict__ srcU, f16 (*A)[64][72], int tid) {
  int row = tid >> 2, ch = tid & 3;
  const ull* s = srcU + row * 128 + ch * 4;
#pragma unroll
  for (int c = 0; c < 8; ++c) {
    ull d0 = ldU(s + c * 16 + 0);
    ull d1 = ldU(s + c * 16 + 1);
    ull d2 = ldU(s + c * 16 + 2);
    ull d3 = ldU(s + c * 16 + 3);
    f16* d = &A[c][row][0];
    *(ull*)(d +  0 + ch * 4) = d0;
    *(ull*)(d + 16 + ch * 4) = d1;
    *(ull*)(d + 32 + ch * 4) = d2;
    *(ull*)(d + 48 + ch * 4) = d3;
  }
}

// 64x32 output tile: wave (mh,ns); acc[2]
DEV void kloop32(const f16 (*Wt)[32][72], const f16 (*A)[64][72],
                 int mh, int ns, int m16, int g4, f32x4 acc[2]) {
#pragma unroll
  for (int c = 0; c < 8; ++c) {
#pragma unroll
    for (int half = 0; half < 2; ++half) {
      f16x8 bf = *(const f16x8*)&Wt[c][ns * 16 + m16][g4 * 16 + half * 8];
      f16x4 bl = lo4(bf), bh = hi4(bf);
#pragma unroll
      for (int mt = 0; mt < 2; ++mt) {
        f16x8 af = *(const f16x8*)&A[c][mh * 32 + mt * 16 + m16][g4 * 16 + half * 8];
        acc[mt] = mfma16(lo4(af), bl, acc[mt]);
        acc[mt] = mfma16(hi4(af), bh, acc[mt]);
      }
    }
  }
}

// 64x64 output tile: wave = n-16-group; acc[4]
DEV void kloop64(const f16* Wg, const f16 (*A)[64][72],
                 int nsG, int m16, int g4, f32x4 acc[4]) {
#pragma unroll
  for (int c = 0; c < 8; ++c) {
#pragma unroll
    for (int half = 0; half < 2; ++half) {
      f16x8 bf = *(const f16x8*)&Wg[((size_t)(c * 64 + nsG * 16 + m16)) * 72 + g4 * 16 + half * 8];
      f16x4 bl = lo4(bf), bh = hi4(bf);
#pragma unroll
      for (int mt = 0; mt < 4; ++mt) {
        f16x8 af = *(const f16x8*)&A[c][mt * 16 + m16][g4 * 16 + half * 8];
        acc[mt] = mfma16(lo4(af), bl, acc[mt]);
        acc[mt] = mfma16(hi4(af), bh, acc[mt]);
      }
    }
  }
}

// ---------------- prologue kernels ----------------

__global__ void k_convert4(const float* __restrict__ src, f16* __restrict__ dst, int n4) {
  int i = blockIdx.x * 256 + threadIdx.x;
  if (i < n4) {
    float4 v = ((const float4*)src)[i];
    f16x4 o = { (f16)v.x, (f16)v.y, (f16)v.z, (f16)v.w };
    *(f16x4*)(dst + (size_t)i * 4) = o;
  }
}

__global__ void k_wc9(const float* __restrict__ src, f16* __restrict__ dst) {
  int i = blockIdx.x * 256 + threadIdx.x;
  if (i < 512 * 4608) {
    int e = i / 4608, k = i % 4608;
    int rr = k / 512, f = k % 512;
    dst[i] = (f16)src[(size_t)e * 4608 + f * 9 + rr];
  }
}

__global__ void k_cfT(const float* __restrict__ cf, f16* __restrict__ dst) {
  int i = blockIdx.x * 256 + threadIdx.x;
  if (i < 64 * 240 * 512) {
    int b = i / (240 * 512), r = i % (240 * 512);
    int p = r / 512, f = r % 512;
    dst[i] = (f16)cf[((size_t)b * 512 + f) * 240 + p];
  }
}

__global__ void k_maxpool(const float* __restrict__ cf, f16* __restrict__ xseq) {
  int i = blockIdx.x * 256 + threadIdx.x;
  if (i < 40 * 64 * 512) {
    int w = i / (64 * 512), r = i % (64 * 512);
    int b = r / 512, f = r % 512;
    const float* base = cf + ((size_t)b * 512 + f) * 240 + w;
    float m = base[0];
#pragma unroll
    for (int h = 1; h < 6; ++h) m = fmaxf(m, base[h * 40]);
    xseq[i] = (f16)m;
  }
}

__global__ void k_ltarget(const int* __restrict__ target, int* __restrict__ lt) {
  int b = threadIdx.x;
  if (b >= 64) return;
  int row[32];
  row[0] = 0;
  for (int t = 1; t <= 30; ++t) row[t] = target[b * 30 + t - 1];
  row[31] = 0;
  int j = 1;
  while (row[j] != 0) ++j;
  row[j] = 95;
  for (int t = 0; t < 32; ++t) lt[b * 32 + t] = row[t];
}

__global__ void k_fill_xs(const f16* __restrict__ hol, const f16* __restrict__ emb,
                          const int* __restrict__ tgt, f16* __restrict__ xs) {
  int i = blockIdx.x * 256 + threadIdx.x;
  if (i < 32 * 64 * 512) {
    int t = i / (64 * 512), r = i % (64 * 512);
    int b = r / 512, u = r % 512;
    f16 v;
    if (t == 0) v = hol[b * 512 + u];
    else {
      int tok = (t == 1) ? 95 : tgt[b * 30 + t - 2];
      v = emb[(size_t)tok * 512 + u];
    }
    xs[i] = v;
  }
}

// ---------------- batched X0 GEMM: C[M][2048] = A[M][512]@W^T + b1+b2 (f16) ----------------
__global__ __launch_bounds__(256) void k_gemmX(
    const f16* __restrict__ A, const f16* __restrict__ W,
    const float* __restrict__ b1, const float* __restrict__ b2,
    f16* __restrict__ C)
{
  __shared__ f16 At[64][72];
  __shared__ f16 Bt[64][72];
  const int t = threadIdx.x, lane = t & 63, g = t >> 6;
  f32x4 acc[4] = {};
  const int m16 = lane & 15, g4 = lane >> 4;
  const size_t arow0 = (size_t)blockIdx.x * 64;

  for (int k0 = 0; k0 < 512; k0 += 64) {
    __syncthreads();
    { int row = t >> 2, ch = t & 3;
      stageRow(A + (arow0 + row) * 512 + k0 + ch * 16, &At[row][0], ch); }
    { int row = t >> 2, ch = t & 3;
      stageRow(W + ((size_t)blockIdx.y * 64 + row) * 512 + k0 + ch * 16, &Bt[row][0], ch); }
    __syncthreads();
#pragma unroll
    for (int half = 0; half < 2; ++half) {
      f16x8 bf = *(const f16x8*)&Bt[g * 16 + m16][g4 * 16 + half * 8];
      f16x4 bl = lo4(bf), bh = hi4(bf);
#pragma unroll
      for (int mt = 0; mt < 4; ++mt) {
        f16x8 af = *(const f16x8*)&At[mt * 16 + m16][g4 * 16 + half * 8];
        acc[mt] = mfma16(lo4(af), bl, acc[mt]);
        acc[mt] = mfma16(hi4(af), bh, acc[mt]);
      }
    }
  }
  int e = blockIdx.y * 64 + g * 16 + m16;
  float bias = b1[e] + b2[e];
#pragma unroll
  for (int mt = 0; mt < 4; ++mt)
#pragma unroll
    for (int r = 0; r < 4; ++r)
      C[(arow0 + mt * 16 + g4 * 4 + r) * 2048 + e] = (f16)(acc[mt][r] + bias);
}

// ---------------- gAll[2048][512] = h1 @ awh^T + bh (f16) ----------------
__global__ __launch_bounds__(256) void k_gemmG(
    const f16* __restrict__ A, const f16* __restrict__ W,
    const float* __restrict__ b1, f16* __restrict__ C)
{
  __shared__ f16 At[64][72];
  __shared__ f16 Bt[64][72];
  const int t = threadIdx.x, lane = t & 63, g = t >> 6;
  f32x4 acc[4] = {};
  const int m16 = lane & 15, g4 = lane >> 4;
  const size_t arow0 = (size_t)blockIdx.x * 64;

  for (int k0 = 0; k0 < 512; k0 += 64) {
    __syncthreads();
    { int row = t >> 2, ch = t & 3;
      stageRow(A + (arow0 + row) * 512 + k0 + ch * 16, &At[row][0], ch); }
    { int row = t >> 2, ch = t & 3;
      stageRow(W + ((size_t)blockIdx.y * 64 + row) * 512 + k0 + ch * 16, &Bt[row][0], ch); }
    __syncthreads();
#pragma unroll
    for (int half = 0; half < 2; ++half) {
      f16x8 bf = *(const f16x8*)&Bt[g * 16 + m16][g4 * 16 + half * 8];
      f16x4 bl = lo4(bf), bh = hi4(bf);
#pragma unroll
      for (int mt = 0; mt < 4; ++mt) {
        f16x8 af = *(const f16x8*)&At[mt * 16 + m16][g4 * 16 + half * 8];
        acc[mt] = mfma16(lo4(af), bl, acc[mt]);
        acc[mt] = mfma16(hi4(af), bh, acc[mt]);
      }
    }
  }
  int e = blockIdx.y * 64 + g * 16 + m16;
  float bias = b1[e];
#pragma unroll
  for (int mt = 0; mt < 4; ++mt)
#pragma unroll
    for (int r = 0; r < 4; ++r)
      C[(arow0 + mt * 16 + g4 * 4 + r) * 512 + e] = (f16)(acc[mt][r] + bias);
}

// ---------------- lgt[2048][96] = ctx[2048][1024] @ outw^T + ob (f32) ----------------
__global__ __launch_bounds__(256) void k_gemmL(
    const f16* __restrict__ A, const f16* __restrict__ W,
    const float* __restrict__ bias, float* __restrict__ C)
{
  __shared__ f16 At[64][72];
  __shared__ f16 Bt[64][72];
  const int t = threadIdx.x, lane = t & 63, g = t >> 6;
  f32x4 acc[4] = {};
  const int m16 = lane & 15, g4 = lane >> 4;
  const size_t arow0 = (size_t)blockIdx.x * 64;

  for (int k0 = 0; k0 < 1024; k0 += 64) {
    __syncthreads();
    { int row = t >> 2, ch = t & 3;
      stageRow(A + (arow0 + row) * 1024 + k0 + ch * 16, &At[row][0], ch); }
    { int row = t >> 2, ch = t & 3;
      stageRow(W + ((size_t)(blockIdx.y * 64 + row)) * 1024 + k0 + ch * 16, &Bt[row][0], ch); }
    __syncthreads();
#pragma unroll
    for (int half = 0; half < 2; ++half) {
      f16x8 bf = *(const f16x8*)&Bt[g * 16 + m16][g4 * 16 + half * 8];
      f16x4 bl = lo4(bf), bh = hi4(bf);
#pragma unroll
      for (int mt = 0; mt < 4; ++mt) {
        f16x8 af = *(const f16x8*)&At[mt * 16 + m16][g4 * 16 + half * 8];
        acc[mt] = mfma16(lo4(af), bl, acc[mt]);
        acc[mt] = mfma16(hi4(af), bh, acc[mt]);
      }
    }
  }
  int e = blockIdx.y * 64 + g * 16 + m16;
  if (e < 96) {
    float be = bias[e];
#pragma unroll
    for (int mt = 0; mt < 4; ++mt)
#pragma unroll
      for (int r = 0; r < 4; ++r)
        C[(arow0 + mt * 16 + g4 * 4 + r) * 96 + e] = acc[mt][r] + be;
  }
}

// ---------------- conv 3x3 as 9 shifted MFMA GEMMs (f16 out) ----------------
__global__ __launch_bounds__(256, 1) void k_conv(
    const f16* __restrict__ cfT, const f16* __restrict__ wc9,
    const float* __restrict__ cb, f16* __restrict__ xemH)
{
  __shared__ f16 At[240][40];
  __shared__ f16 Bt[128][40];
  const int t = threadIdx.x, lane = t & 63, w = t >> 6;
  const int b = blockIdx.y, eb = blockIdx.x * 128;
  const int m16 = lane & 15, g4 = lane >> 4;
  f32x4 acc[15][2] = {};

  for (int kr = 0; kr < 9; ++kr) {
    int dh = kr / 3 - 1, dw = kr % 3 - 1;
    for (int f0 = 0; f0 < 512; f0 += 32) {
      __syncthreads();
      if (t < 240) {
        int hh = t / 40 + dh, ww = t % 40 + dw;
        if (hh >= 0 && hh < 6 && ww >= 0 && ww < 40) {
          const f16* s = cfT + ((size_t)(b * 240 + hh * 40 + ww) * 512 + f0);
          U8 u0, u1, u2, u3;
          u0.f4 = *(const float4*)s;        u1.f4 = *(const float4*)(s + 8);
          u2.f4 = *(const float4*)(s + 16); u3.f4 = *(const float4*)(s + 24);
          *(float2*)&At[t][ 0] = u0.f2[0];
          *(float2*)&At[t][ 8] = u0.f2[1];
          *(float2*)&At[t][16] = u1.f2[0];
          *(float2*)&At[t][24] = u1.f2[1];
          *(float2*)&At[t][ 4] = u2.f2[0];
          *(float2*)&At[t][12] = u2.f2[1];
          *(float2*)&At[t][20] = u3.f2[0];
          *(float2*)&At[t][28] = u3.f2[1];
        } else {
          float2 z = make_float2(0.f, 0.f);
          *(float2*)&At[t][ 0] = z; *(float2*)&At[t][ 8] = z;
          *(float2*)&At[t][16] = z; *(float2*)&At[t][24] = z;
          *(float2*)&At[t][ 4] = z; *(float2*)&At[t][12] = z;
          *(float2*)&At[t][20] = z; *(float2*)&At[t][28] = z;
        }
      }
      {
        int n = t >> 1, ch = t & 1;
        const f16* s = wc9 + (size_t)(eb + n) * 4608 + kr * 512 + f0 + ch * 16;
        U8 u0, u1;
        u0.f4 = *(const float4*)s; u1.f4 = *(const float4*)(s + 8);
        *(float2*)&Bt[n][ 0 + ch * 4] = u0.f2[0];
        *(float2*)&Bt[n][ 8 + ch * 4] = u0.f2[1];
        *(float2*)&Bt[n][16 + ch * 4] = u1.f2[0];
        *(float2*)&Bt[n][24 + ch * 4] = u1.f2[1];
      }
      __syncthreads();
      f16x8 b0 = *(const f16x8*)&Bt[w * 32 + m16][g4 * 8];
      f16x8 b1v = *(const f16x8*)&Bt[w * 32 + 16 + m16][g4 * 8];
      f16x4 b0l = lo4(b0), b0h = hi4(b0), b1l = lo4(b1v), b1h = hi4(b1v);
#pragma unroll
      for (int mt = 0; mt < 15; ++mt) {
        f16x8 af = *(const f16x8*)&At[mt * 16 + m16][g4 * 8];
        f16x4 al = lo4(af), ah = hi4(af);
        acc[mt][0] = mfma16(al, b0l, acc[mt][0]);
        acc[mt][1] = mfma16(al, b1l, acc[mt][1]);
        acc[mt][0] = mfma16(ah, b0h, acc[mt][0]);
        acc[mt][1] = mfma16(ah, b1h, acc[mt][1]);
      }
    }
  }
#pragma unroll
  for (int nt = 0; nt < 2; ++nt) {
    int e = eb + w * 32 + nt * 16 + m16;
    float bias = cb[e];
#pragma unroll
    for (int mt = 0; mt < 15; ++mt)
#pragma unroll
      for (int r = 0; r < 4; ++r) {
        int p = mt * 16 + g4 * 4 + r;
        xemH[((size_t)(b * 240 + p)) * 512 + e] = (f16)(acc[mt][nt][r] + bias);
      }
  }
}

// ---------------- persistent 2-layer LSTM (dataflow sync, no global barrier) ----------------
// blocks [0,32) = L0 (16 u-cols each), [32,96) = L1 (8 u-cols each)
// cnt layout: [stage][t] lines of 8 slots (slot stride 16 dwords)
__global__ __launch_bounds__(256, 1) void k_lstm(
    int T,
    const f16* __restrict__ G0, const f16* __restrict__ whh0,
    const f16* __restrict__ wih1, const f16* __restrict__ whh1,
    const float* __restrict__ bih1, const float* __restrict__ bhh1,
    f16* __restrict__ h0seq, f16* __restrict__ h1seq,
    unsigned* __restrict__ cnt)
{
  __shared__ __align__(16) char smem[147456];
  const int tid = threadIdx.x, lane = tid & 63, w = tid >> 6;
  const int m16 = lane & 15, g4 = lane >> 4;
  const int bid = blockIdx.x;
  unsigned* h0U32 = (unsigned*)h0seq;
  unsigned* h1U32 = (unsigned*)h1seq;

  if (bid < 32) {  // ---------- layer 0 ----------
    f16 (*sW)[64][72] = (f16(*)[64][72])smem;
    f16 (*sA)[64][72] = (f16(*)[64][72])(smem + 73728);
    float* sG = (float*)(smem + 73728);   // [4][64][17]
    const int utile = bid;
    { int r = tid >> 2, ch = tid & 3;
      int grow = (r >> 4) * 512 + utile * 16 + (r & 15);
      for (int c = 0; c < 8; ++c)
        stageRow(whh0 + (size_t)grow * 512 + c * 64 + ch * 16, &sW[c][r][0], ch);
    }
    float cst[2][2] = {};
    for (int t = 0; t < T; ++t) {
      if (t > 0) waitTwo(cnt + (t - 1) * 128, 4, cnt + (t - 1) * 128, 4);
      stageAu((const ull*)h0seq + (size_t)t * 8192, sA, tid);
      __syncthreads();
      f32x4 acc[4] = {};
      kloop64((const f16*)sW, sA, w, m16, g4, acc);
      __syncthreads();
#pragma unroll
      for (int mt = 0; mt < 4; ++mt)
#pragma unroll
        for (int r = 0; r < 4; ++r)
          sG[((size_t)w * 64 + mt * 16 + g4 * 4 + r) * 17 + m16] = acc[mt][r];
      __syncthreads();
#pragma unroll
      for (int k = 0; k < 2; ++k) {
        int pi = tid + k * 256;
        int b = pi >> 3, up = pi & 7;
        const unsigned* gp = (const unsigned*)G0 + (size_t)(t * 64 + b) * 1024 + utile * 8 + up;
        H2 gI, gF, gG, gO, outp;
        gI.u = gp[0]; gF.u = gp[256]; gG.u = gp[512]; gO.u = gp[768];
#pragma unroll
        for (int j = 0; j < 2; ++j) {
          int u = up * 2 + j;
          float gi = sG[(0 * 64 + b) * 17 + u] + (float)gI.h[j];
          float gf = sG[(1 * 64 + b) * 17 + u] + (float)gF.h[j];
          float gg = sG[(2 * 64 + b) * 17 + u] + (float)gG.h[j];
          float go = sG[(3 * 64 + b) * 17 + u] + (float)gO.h[j];
          float cn = sigf(gf) * cst[k][j] + sigf(gi) * tanh_(gg);
          float hn = sigf(go) * tanh_(cn);
          cst[k][j] = cn;
          outp.h[j] = (f16)hn;
        }
        stU32(h0U32 + (size_t)(t + 1) * 16384 + b * 256 + utile * 8 + up, outp.u);
      }
      signalDone(cnt + t * 128, bid & 7);
    }
  } else {  // ---------- layer 1 ----------
    f16 (*sW2)[8][32][72] = (f16(*)[8][32][72])smem;
    f16 (*sA)[64][72] = (f16(*)[64][72])(smem + 73728);
    float* sG = (float*)(smem + 73728);   // [4][64][9]
    const int utile = bid - 32;
    const int mh = w >> 1, ns = w & 1;
    { int mat = tid >> 7;
      int r = (tid >> 2) & 31, ch = tid & 3;
      int grow = (r >> 3) * 512 + utile * 8 + (r & 7);
      const f16* Wsrc = (mat == 0) ? wih1 : whh1;
      for (int c = 0; c < 8; ++c)
        stageRow(Wsrc + (size_t)grow * 512 + c * 64 + ch * 16, &sW2[mat][c][r][0], ch);
    }
    const int pb = tid >> 2, pup = tid & 3;
    float badd[4][2];
#pragma unroll
    for (int g = 0; g < 4; ++g)
#pragma unroll
      for (int j = 0; j < 2; ++j) {
        int rr = g * 512 + utile * 8 + pup * 2 + j;
        badd[g][j] = bih1[rr] + bhh1[rr];
      }
    float cst[2] = {0.f, 0.f};
    unsigned* cnt1 = cnt + (size_t)T * 128;
    for (int t = 0; t < T; ++t) {
      if (t > 0) waitTwo(cnt + t * 128, 4, cnt1 + (t - 1) * 128, 8);
      else       waitTwo(cnt, 4, cnt, 4);
      f32x4 acc[2] = {};
      stageAu((const ull*)h0seq + (size_t)(t + 1) * 8192, sA, tid);   // h0(t)
      __syncthreads();
      kloop32(sW2[0], sA, mh, ns, m16, g4, acc);
      __syncthreads();
      stageAu((const ull*)h1seq + (size_t)t * 8192, sA, tid);         // h1(t-1)
      __syncthreads();
      kloop32(sW2[1], sA, mh, ns, m16, g4, acc);
      __syncthreads();
      { int nl = ns * 16 + m16;
#pragma unroll
        for (int mt = 0; mt < 2; ++mt)
#pragma unroll
          for (int r = 0; r < 4; ++r) {
            int b = mh * 32 + mt * 16 + g4 * 4 + r;
            sG[((nl >> 3) * 64 + b) * 9 + (nl & 7)] = acc[mt][r];
          }
      }
      __syncthreads();
      {
        H2 outp;
#pragma unroll
        for (int j = 0; j < 2; ++j) {
          int u = pup * 2 + j;
          float gi = sG[(0 * 64 + pb) * 9 + u] + badd[0][j];
          float gf = sG[(1 * 64 + pb) * 9 + u] + badd[1][j];
          float gg = sG[(2 * 64 + pb) * 9 + u] + badd[2][j];
          float go = sG[(3 * 64 + pb) * 9 + u] + badd[3][j];
          float cn = sigf(gf) * cst[j] + sigf(gi) * tanh_(gg);
          float hn = sigf(go) * tanh_(cn);
          cst[j] = cn;
          outp.h[j] = (f16)hn;
        }
        stU32(h1U32 + (size_t)(t + 1) * 16384 + pb * 256 + utile * 4 + pup, outp.u);
      }
      signalDone(cnt1 + t * 128, bid & 7);
    }
  }
}

// ---------------- batched attention post-pass ----------------

// scores e[t][b][hw] for all t; grid (6 tiles, 64 b)
__global__ __launch_bounds__(256) void k_scoreAll(
    const f16* __restrict__ xemH, const f16* __restrict__ gAll,
    const float* __restrict__ wv, float* __restrict__ esc)
{
  __shared__ f16 sX[40][512];
  const int tid = threadIdx.x, lane = tid & 63, w = tid >> 6;
  const int tile = blockIdx.x, b = blockIdx.y;
  for (int i = tid; i < 40 * 64; i += 256) {
    int row = i >> 6, seg = i & 63;
    *(f16x8*)&sX[row][seg * 8] =
        *(const f16x8*)(xemH + ((size_t)(b * 240 + tile * 40 + row)) * 512 + seg * 8);
  }
  float w8[8];
  { const float4* wp = (const float4*)(wv + lane * 8);
    float4 wa = wp[0], wb = wp[1];
    w8[0] = wa.x; w8[1] = wa.y; w8[2] = wa.z; w8[3] = wa.w;
    w8[4] = wb.x; w8[5] = wb.y; w8[6] = wb.z; w8[7] = wb.w; }
  __syncthreads();
  for (int t = 0; t < 32; ++t) {
    f16x8 gv = *(const f16x8*)(gAll + ((size_t)(t * 64 + b)) * 512 + lane * 8);
    float g8[8];
#pragma unroll
    for (int j = 0; j < 8; ++j) g8[j] = (float)gv[j];
#pragma unroll
    for (int i = 0; i < 10; ++i) {
      int rr = i * 4 + w;
      f16x8 xv = *(const f16x8*)&sX[rr][lane * 8];
      float s = 0.f;
#pragma unroll
      for (int j = 0; j < 8; ++j) s += tanh_((float)xv[j] + g8[j]) * w8[j];
#pragma unroll
      for (int m = 32; m; m >>= 1) s += __shfl_xor(s, m);
      if (lane == 0) esc[((size_t)(t * 64 + b)) * 240 + tile * 40 + rr] = s;
    }
  }
}

// softmax over hw + context + ctx concat fill; grid (4 t-quarters, 64 b)
__global__ __launch_bounds__(256) void k_smctx(
    const float* __restrict__ esc, const f16* __restrict__ cfT,
    const f16* __restrict__ h1seq, f16* __restrict__ ctx)
{
  __shared__ float aAl[8][240];
  const int tid = threadIdx.x, lane = tid & 63, w = tid >> 6;
  const int tq = blockIdx.x, b = blockIdx.y;
  for (int half = 0; half < 2; ++half) {
    int tt = w + half * 4;
    int t = tq * 8 + tt;
    const float* er = esc + ((size_t)(t * 64 + b)) * 240;
    float v[4];
    float mx = -1e30f;
#pragma unroll
    for (int q = 0; q < 4; ++q) {
      int p = lane + q * 64;
      v[q] = (p < 240) ? er[p] : -1e30f;
      mx = fmaxf(mx, v[q]);
    }
#pragma unroll
    for (int m = 32; m; m >>= 1) mx = fmaxf(mx, __shfl_xor(mx, m));
    float sum = 0.f;
#pragma unroll
    for (int q = 0; q < 4; ++q) { v[q] = __expf(v[q] - mx); sum += v[q]; }
#pragma unroll
    for (int m = 32; m; m >>= 1) sum += __shfl_xor(sum, m);
    float inv = 1.f / sum;
#pragma unroll
    for (int q = 0; q < 4; ++q) {
      int p = lane + q * 64;
      if (p < 240) aAl[tt][p] = v[q] * inv;
    }
  }
  __syncthreads();
  float acc[8][2] = {};
  const f16* cb = cfT + (size_t)b * 240 * 512;
  for (int p = 0; p < 240; ++p) {
    H2 cw; cw.u = *(const unsigned*)(cb + (size_t)p * 512 + tid * 2);
    float c0 = (float)cw.h[0], c1 = (float)cw.h[1];
#pragma unroll
    for (int tt = 0; tt < 8; ++tt) {
      float a = aAl[tt][p];
      acc[tt][0] += a * c0;
      acc[tt][1] += a * c1;
    }
  }
#pragma unroll
  for (int tt = 0; tt < 8; ++tt) {
    int t = tq * 8 + tt;
    size_t r = (size_t)(t * 64 + b);
    H2 o; o.h[0] = (f16)acc[tt][0]; o.h[1] = (f16)acc[tt][1];
    *(unsigned*)(ctx + r * 1024 + 512 + tid * 2) = o.u;
    *(unsigned*)(ctx + r * 1024 + tid * 2) =
        *(const unsigned*)(h1seq + (size_t)(t + 1) * HB + b * 512 + tid * 2);
  }
}

__global__ void k_nll(const float* __restrict__ lgt, const int* __restrict__ ltg,
                      float* __restrict__ nllb)
{
  int r = blockIdx.x * 256 + threadIdx.x;
  if (r >= 2048) return;
  int t = r >> 6, b = r & 63;
  const float* row = lgt + (size_t)r * 96;
  float mx = -1e30f;
  for (int j = 0; j < 96; ++j) mx = fmaxf(mx, row[j]);
  float sum = 0.f;
  for (int j = 0; j < 96; ++j) sum += __expf(row[j] - mx);
  float lse = mx + __logf(sum);
  int tok = ltg[b * 32 + t];
  nllb[r] = (tok != 0) ? (lse - row[tok]) : 0.f;
}

__global__ void k_loss(const float* __restrict__ nll, const int* __restrict__ ltg,
                       float* __restrict__ out) {
  __shared__ float sa[256], sb[256];
  int t = threadIdx.x;
  float a = 0.f, m = 0.f;
  for (int i = t; i < 2048; i += 256) {
    a += nll[i];
    m += (ltg[i] != 0) ? 1.f : 0.f;
  }
  sa[t] = a; sb[t] = m; __syncthreads();
  for (int s = 128; s; s >>= 1) { if (t < s) { sa[t] += sa[t + s]; sb[t] += sb[t + s]; } __syncthreads(); }
  if (t == 0) out[0] = sa[0] / sb[0];
}

// ---------------- host ----------------

extern "C" void kernel_launch(void* const* d_in, const int* in_sizes, int n_in,
                              void* d_out, int out_size, void* d_ws, size_t ws_size,
                              hipStream_t stream) {
  (void)in_sizes; (void)n_in; (void)out_size; (void)ws_size;
  const float* conv_f = (const float*)d_in[0];
  const int*   target = (const int*)d_in[1];
  const float* wih_en = (const float*)d_in[2];
  const float* whh_en = (const float*)d_in[3];
  const float* bih_en = (const float*)d_in[4];
  const float* bhh_en = (const float*)d_in[5];
  const float* embed  = (const float*)d_in[6];
  const float* wih_de = (const float*)d_in[7];
  const float* whh_de = (const float*)d_in[8];
  const float* bih_de = (const float*)d_in[9];
  const float* bhh_de = (const float*)d_in[10];
  const float* att_wh = (const float*)d_in[11];
  const float* att_bh = (const float*)d_in[12];
  const float* att_cw = (const float*)d_in[13];
  const float* att_cb = (const float*)d_in[14];
  const float* att_wv = (const float*)d_in[15];
  const float* out_w  = (const float*)d_in[17];
  const float* out_b  = (const float*)d_in[18];
  float* out = (float*)d_out;

  size_t o = 0;
  char* base = (char*)d_ws;
  auto take = [&](size_t bytes) -> void* {
    void* p = base + o;
    o += (bytes + 255) & ~(size_t)255;
    return p;
  };
  const size_t WSZ = (size_t)2048 * 512;
  f16* wihEn = (f16*)take(2 * WSZ * 2);
  f16* whhEn = (f16*)take(2 * WSZ * 2);
  f16* wihDe = (f16*)take(2 * WSZ * 2);
  f16* whhDe = (f16*)take(2 * WSZ * 2);
  f16* awh   = (f16*)take((size_t)512 * 512 * 2);
  f16* emb   = (f16*)take((size_t)96 * 512 * 2);
  f16* wc9   = (f16*)take((size_t)512 * 4608 * 2);
  f16* cfT   = (f16*)take((size_t)64 * 240 * 512 * 2);
  f16* xseq  = (f16*)take((size_t)40 * 64 * 512 * 2);
  f16* xs    = (f16*)take((size_t)32 * 64 * 512 * 2);
  f16* xemH  = (f16*)take((size_t)64 * 240 * 512 * 2);
  f16* outwH = (f16*)take((size_t)128 * 1024 * 2);
  f16* X0en  = (f16*)take((size_t)2560 * 2048 * 2);
  f16* X0de  = (f16*)take((size_t)2048 * 2048 * 2);
  f16* h0seqE = (f16*)take((size_t)41 * HB * 2);
  f16* h1seqE = (f16*)take((size_t)41 * HB * 2);
  f16* h0seqD = (f16*)take((size_t)33 * HB * 2);
  f16* h1seqD = (f16*)take((size_t)33 * HB * 2);
  f16* gAll   = (f16*)take((size_t)2048 * 512 * 2);
  float* nllb  = (float*)take((size_t)2048 * 4);
  int*   ltg   = (int*)take((size_t)2048 * 4);
  unsigned* cntE = (unsigned*)take((size_t)2 * 40 * 8 * 64);
  unsigned* cntD = (unsigned*)take((size_t)2 * 32 * 8 * 64);
  // aliases onto dead precompute buffers (post-pass runs after their last read)
  float* escAll = (float*)X0en;                          // 2048*240*4 = 1.97 MB
  float* lgtAll = (float*)((char*)X0en + 4194304);       // 2048*96*4
  f16*   ctxAll = X0de;                                  // 2048*1024*2 = 4.2 MB

  // prologue conversions
  k_convert4<<<2048, 256, 0, stream>>>(wih_en, wihEn, (int)(2 * WSZ / 4));
  k_convert4<<<2048, 256, 0, stream>>>(whh_en, whhEn, (int)(2 * WSZ / 4));
  k_convert4<<<2048, 256, 0, stream>>>(wih_de, wihDe, (int)(2 * WSZ / 4));
  k_convert4<<<2048, 256, 0, stream>>>(whh_de, whhDe, (int)(2 * WSZ / 4));
  k_convert4<<<256, 256, 0, stream>>>(att_wh, awh, 512 * 512 / 4);
  k_convert4<<<48, 256, 0, stream>>>(embed, emb, 96 * 512 / 4);
  k_convert4<<<96, 256, 0, stream>>>(out_w, outwH, 96 * 1024 / 4);
  k_wc9<<<(512 * 4608 + 255) / 256, 256, 0, stream>>>(att_cw, wc9);
  k_cfT<<<(64 * 240 * 512 + 255) / 256, 256, 0, stream>>>(conv_f, cfT);
  k_maxpool<<<(40 * 64 * 512 + 255) / 256, 256, 0, stream>>>(conv_f, xseq);
  k_ltarget<<<1, 64, 0, stream>>>(target, ltg);
  hipMemsetAsync(h0seqE, 0, (size_t)HB * 2, stream);
  hipMemsetAsync(h1seqE, 0, (size_t)HB * 2, stream);
  hipMemsetAsync(h0seqD, 0, (size_t)HB * 2, stream);
  hipMemsetAsync(h1seqD, 0, (size_t)HB * 2, stream);
  hipMemsetAsync(cntE, 0, (size_t)2 * 40 * 8 * 64 + (size_t)2 * 32 * 8 * 64, stream);

  k_conv<<<dim3(4, 64), 256, 0, stream>>>(cfT, wc9, att_cb, xemH);
  k_gemmX<<<dim3(40, 32), 256, 0, stream>>>(xseq, wihEn, bih_en, bhh_en, X0en);

  k_lstm<<<96, 256, 0, stream>>>(40, X0en, whhEn, wihEn + WSZ, whhEn + WSZ,
                                 bih_en + 2048, bhh_en + 2048, h0seqE, h1seqE, cntE);

  k_fill_xs<<<(32 * 64 * 512 + 255) / 256, 256, 0, stream>>>(h1seqE + (size_t)40 * HB, emb, target, xs);
  k_gemmX<<<dim3(32, 32), 256, 0, stream>>>(xs, wihDe, bih_de, bhh_de, X0de);

  k_lstm<<<96, 256, 0, stream>>>(32, X0de, whhDe, wihDe + WSZ, whhDe + WSZ,
                                 bih_de + 2048, bhh_de + 2048, h0seqD, h1seqD, cntD);

  // batched attention + logits post-pass
  k_gemmG<<<dim3(32, 8), 256, 0, stream>>>(h1seqD + HB, awh, att_bh, gAll);
  k_scoreAll<<<dim3(6, 64), 256, 0, stream>>>(xemH, gAll, att_wv, escAll);
  k_smctx<<<dim3(4, 64), 256, 0, stream>>>(escAll, cfT, h1seqD, ctxAll);
  k_gemmL<<<dim3(32, 2), 256, 0, stream>>>(ctxAll, outwH, out_b, lgtAll);
  k_nll<<<8, 256, 0, stream>>>(lgtAll, ltg, nllb);
  k_loss<<<1, 256, 0, stream>>>(nllb, ltg, out);
}